// Round 1
// baseline (526.103 us; speedup 1.0000x reference)
//
#include <hip/hip_runtime.h>
#include <math.h>

// Net_19335942767008: per-agent CNN (3x conv3x3+BN+ReLU+pool) -> FC -> GCNx2 -> head
// B=256, N=64 -> S=16384 samples. All fp32 baseline (round 0).

#define S_TOT 16384

// ---------------- conv1: [S,3,8,8] -> pooled [S,32,4,4] ----------------
__global__ __launch_bounds__(256) void conv1_kernel(
    const float* __restrict__ x, const float* __restrict__ w,
    const float* __restrict__ b, const float* __restrict__ g,
    const float* __restrict__ be, float* __restrict__ out) {
  __shared__ float s_in[192];   // 3*8*8
  __shared__ float s_w[864];    // 32*3*3*3
  __shared__ float s_A[32], s_C[32];
  const int s = blockIdx.x;
  const int tid = threadIdx.x;
  if (tid < 192) s_in[tid] = x[s * 192 + tid];
  for (int i = tid; i < 864; i += 256) s_w[i] = w[i];
  if (tid < 32) {
    float sc = g[tid] * rsqrtf(1.0f + 1e-5f);
    s_A[tid] = sc;
    s_C[tid] = fmaf(b[tid], sc, be[tid]);
  }
  __syncthreads();
  for (int o = tid; o < 512; o += 256) {
    const int oc = o >> 4;
    const int py = (o >> 2) & 3;
    const int px = o & 3;
    float best = 0.0f;
    for (int dy = 0; dy < 2; ++dy)
      for (int dx = 0; dx < 2; ++dx) {
        const int cy = 2 * py + dy, cx = 2 * px + dx;
        float acc = 0.0f;
        for (int ic = 0; ic < 3; ++ic)
          for (int ky = 0; ky < 3; ++ky) {
            const int yy = cy + ky - 1;
            if ((unsigned)yy < 8u)
              for (int kx = 0; kx < 3; ++kx) {
                const int xx = cx + kx - 1;
                if ((unsigned)xx < 8u)
                  acc = fmaf(s_w[((oc * 3 + ic) * 3 + ky) * 3 + kx],
                             s_in[ic * 64 + yy * 8 + xx], acc);
              }
          }
        best = fmaxf(best, fmaxf(fmaf(acc, s_A[oc], s_C[oc]), 0.0f));
      }
    out[s * 512 + o] = best;  // o == oc*16 + py*4 + px
  }
}

// ---------------- conv2: [S,32,4,4] -> pooled [S,64,2,2] ----------------
// block = 4 samples x 64 oc; weights staged in 2 ic-chunks, LDS layout [rem][oc] pad 65
__global__ __launch_bounds__(256) void conv2_kernel(
    const float* __restrict__ in, const float* __restrict__ w,
    const float* __restrict__ b, const float* __restrict__ g,
    const float* __restrict__ be, float* __restrict__ out) {
  __shared__ float s_in[4 * 512];
  __shared__ float s_w[144 * 65];
  __shared__ float s_A[64], s_C[64];
  const int tid = threadIdx.x;
  const int oc = tid & 63;
  const int si = tid >> 6;            // 0..3 sample-in-block
  const int s0 = blockIdx.x * 4;
  for (int i = tid; i < 2048; i += 256) s_in[i] = in[s0 * 512 + i];
  if (tid < 64) {
    float sc = g[tid] * rsqrtf(1.0f + 1e-5f);
    s_A[tid] = sc;
    s_C[tid] = fmaf(b[tid], sc, be[tid]);
  }
  float acc[4][4];
  for (int i = 0; i < 4; ++i)
    for (int j = 0; j < 4; ++j) acc[i][j] = 0.0f;
  for (int chunk = 0; chunk < 2; ++chunk) {
    __syncthreads();
    for (int i = tid; i < 9216; i += 256) {
      const int ocw = i / 144;
      const int rem = i % 144;        // icl*9 + k
      s_w[rem * 65 + ocw] = w[ocw * 288 + chunk * 144 + rem];
    }
    __syncthreads();
    for (int icl = 0; icl < 16; ++icl) {
      const float* inp = &s_in[si * 512 + (chunk * 16 + icl) * 16];
      float wv[9];
      for (int k = 0; k < 9; ++k) wv[k] = s_w[(icl * 9 + k) * 65 + oc];
      for (int ky = 0; ky < 3; ++ky)
        for (int kx = 0; kx < 3; ++kx) {
          const float wk = wv[ky * 3 + kx];
          for (int cy = 0; cy < 4; ++cy) {
            const int yy = cy + ky - 1;
            if ((unsigned)yy >= 4u) continue;
            for (int cx = 0; cx < 4; ++cx) {
              const int xx = cx + kx - 1;
              if ((unsigned)xx >= 4u) continue;
              acc[cy][cx] = fmaf(wk, inp[yy * 4 + xx], acc[cy][cx]);
            }
          }
        }
    }
  }
  const float A = s_A[oc], C = s_C[oc];
  const int s = s0 + si;
  for (int py = 0; py < 2; ++py)
    for (int px = 0; px < 2; ++px) {
      float best = 0.0f;
      for (int dy = 0; dy < 2; ++dy)
        for (int dx = 0; dx < 2; ++dx)
          best = fmaxf(best, fmaxf(fmaf(acc[2 * py + dy][2 * px + dx], A, C), 0.0f));
      out[s * 256 + oc * 4 + py * 2 + px] = best;
    }
}

// ---------------- conv3: [S,64,2,2] -> pooled [S,128] ----------------
// block = 8 samples x 128 oc (each thread 4 samples); 8 ic-chunks, LDS [rem][oc] pad 129
__global__ __launch_bounds__(256) void conv3_kernel(
    const float* __restrict__ in, const float* __restrict__ w,
    const float* __restrict__ b, const float* __restrict__ g,
    const float* __restrict__ be, float* __restrict__ out) {
  __shared__ float s_in[8 * 256];
  __shared__ float s_w[72 * 129];
  __shared__ float s_A[128], s_C[128];
  const int tid = threadIdx.x;
  const int oc = tid & 127;
  const int sub = tid >> 7;           // 0..1
  const int s0 = blockIdx.x * 8;
  for (int i = tid; i < 2048; i += 256) s_in[i] = in[s0 * 256 + i];
  if (tid < 128) {
    float sc = g[tid] * rsqrtf(1.0f + 1e-5f);
    s_A[tid] = sc;
    s_C[tid] = fmaf(b[tid], sc, be[tid]);
  }
  float acc[4][4];  // [sample r][conv pos]
  for (int i = 0; i < 4; ++i)
    for (int j = 0; j < 4; ++j) acc[i][j] = 0.0f;
  for (int chunk = 0; chunk < 8; ++chunk) {
    __syncthreads();
    for (int i = tid; i < 9216; i += 256) {
      const int ocw = i / 72;
      const int rem = i % 72;         // icl*9 + k
      s_w[rem * 129 + ocw] = w[ocw * 576 + chunk * 72 + rem];
    }
    __syncthreads();
    for (int icl = 0; icl < 8; ++icl) {
      float wv[9];
      for (int k = 0; k < 9; ++k) wv[k] = s_w[(icl * 9 + k) * 129 + oc];
      const int ic = chunk * 8 + icl;
      for (int r = 0; r < 4; ++r) {
        const float* inp = &s_in[(sub * 4 + r) * 256 + ic * 4];
        for (int ky = 0; ky < 3; ++ky)
          for (int kx = 0; kx < 3; ++kx) {
            const float wk = wv[ky * 3 + kx];
            for (int y = 0; y < 2; ++y) {
              const int iy = y + ky - 1;
              if ((unsigned)iy >= 2u) continue;
              for (int x2 = 0; x2 < 2; ++x2) {
                const int ix = x2 + kx - 1;
                if ((unsigned)ix >= 2u) continue;
                acc[r][y * 2 + x2] = fmaf(wk, inp[iy * 2 + ix], acc[r][y * 2 + x2]);
              }
            }
          }
      }
    }
  }
  const float A = s_A[oc], C = s_C[oc];
  for (int r = 0; r < 4; ++r) {
    float best = 0.0f;
    for (int p = 0; p < 4; ++p)
      best = fmaxf(best, fmaxf(fmaf(acc[r][p], A, C), 0.0f));
    out[(s0 + sub * 4 + r) * 128 + oc] = best;
  }
}

// ---------------- ahat: gso[b] + I, sym-normalized ----------------
__global__ __launch_bounds__(256) void ahat_kernel(
    const float* __restrict__ gso, float* __restrict__ ahat) {
  __shared__ float s_a[4096];
  __shared__ float s_d[64];
  const int bb = blockIdx.x;
  const int tid = threadIdx.x;
  for (int i = tid; i < 4096; i += 256) {
    const int r = i >> 6, c = i & 63;
    s_a[i] = gso[bb * 4096 + i] + (r == c ? 1.0f : 0.0f);
  }
  __syncthreads();
  if (tid < 64) {
    float sum = 0.0f;
    for (int j = 0; j < 64; ++j) sum += s_a[j * 64 + tid];  // symmetric: col sum == row sum
    s_d[tid] = rsqrtf(sum);
  }
  __syncthreads();
  for (int i = tid; i < 4096; i += 256) {
    const int r = i >> 6, c = i & 63;
    ahat[bb * 4096 + i] = s_d[r] * s_a[i] * s_d[c];
  }
}

// ---------------- generic X[M,128] @ W[128,128]^T (+bias, relu) ----------------
// block = 16 samples x 128 out; k staged in 4 chunks of 32, LDS [kc][n] pad 129
__global__ __launch_bounds__(256) void gemm128_kernel(
    const float* __restrict__ X, const float* __restrict__ Wt,
    const float* __restrict__ bias, float* __restrict__ out, int relu) {
  __shared__ float s_x[16 * 128];
  __shared__ float s_w[32 * 129];
  const int tid = threadIdx.x;
  const int n = tid & 127;
  const int sr = tid >> 7;  // 0..1
  const int s0 = blockIdx.x * 16;
  for (int i = tid; i < 2048; i += 256) s_x[i] = X[s0 * 128 + i];
  float acc[8];
  for (int r = 0; r < 8; ++r) acc[r] = 0.0f;
  for (int chunk = 0; chunk < 4; ++chunk) {
    __syncthreads();
    for (int i = tid; i < 4096; i += 256) {
      const int nw = i >> 5;
      const int kc = i & 31;
      s_w[kc * 129 + nw] = Wt[nw * 128 + chunk * 32 + kc];
    }
    __syncthreads();
    for (int kc = 0; kc < 32; ++kc) {
      const float wv = s_w[kc * 129 + n];
      const int k = chunk * 32 + kc;
      for (int r = 0; r < 8; ++r)
        acc[r] = fmaf(wv, s_x[(sr + 2 * r) * 128 + k], acc[r]);
    }
  }
  const float bv = bias ? bias[n] : 0.0f;
  for (int r = 0; r < 8; ++r) {
    float v = acc[r] + bv;
    if (relu) v = fmaxf(v, 0.0f);
    out[(s0 + sr + 2 * r) * 128 + n] = v;
  }
}

// ---------------- agg: out[b] = relu(ahat[b] @ T[b] + bias) ----------------
// grid (256 batches, 2 feature halves); block = 4 row-groups x 64 features
__global__ __launch_bounds__(256) void agg_kernel(
    const float* __restrict__ ahat, const float* __restrict__ T,
    const float* __restrict__ bias, float* __restrict__ out) {
  __shared__ float s_a[4096];
  __shared__ float s_t[4096];
  const int bb = blockIdx.x;
  const int half = blockIdx.y;
  const int tid = threadIdx.x;
  const int c = tid & 63;
  const int f = (half << 6) + c;
  const int ib = tid >> 6;  // 0..3
  for (int i = tid; i < 4096; i += 256) s_a[i] = ahat[bb * 4096 + i];
  for (int i = tid; i < 4096; i += 256) {
    const int j = i >> 6, cc = i & 63;
    s_t[i] = T[bb * 8192 + j * 128 + (half << 6) + cc];
  }
  __syncthreads();
  float acc[16];
  for (int r = 0; r < 16; ++r) acc[r] = 0.0f;
  for (int j = 0; j < 64; ++j) {
    const float tv = s_t[j * 64 + c];
    for (int r = 0; r < 16; ++r)
      acc[r] = fmaf(s_a[(ib + 4 * r) * 64 + j], tv, acc[r]);
  }
  const float bv = bias[f];
  for (int r = 0; r < 16; ++r) {
    const int i = ib + 4 * r;
    out[bb * 8192 + i * 128 + f] = fmaxf(acc[r] + bv, 0.0f);
  }
}

// ---------------- head: [S,128] @ w_out[5,128]^T + b ----------------
__global__ __launch_bounds__(256) void head_kernel(
    const float* __restrict__ H, const float* __restrict__ Wo,
    const float* __restrict__ bo, float* __restrict__ out) {
  __shared__ float s_w[640];
  __shared__ float s_b[5];
  const int tid = threadIdx.x;
  for (int i = tid; i < 640; i += 256) s_w[i] = Wo[i];
  if (tid < 5) s_b[tid] = bo[tid];
  __syncthreads();
  const int s = blockIdx.x * 256 + tid;
  const float4* h4 = (const float4*)(H + s * 128);
  float acc[5] = {0.f, 0.f, 0.f, 0.f, 0.f};
  for (int k4 = 0; k4 < 32; ++k4) {
    const float4 h = h4[k4];
    for (int o = 0; o < 5; ++o) {
      acc[o] = fmaf(h.x, s_w[o * 128 + k4 * 4 + 0], acc[o]);
      acc[o] = fmaf(h.y, s_w[o * 128 + k4 * 4 + 1], acc[o]);
      acc[o] = fmaf(h.z, s_w[o * 128 + k4 * 4 + 2], acc[o]);
      acc[o] = fmaf(h.w, s_w[o * 128 + k4 * 4 + 3], acc[o]);
    }
  }
  for (int o = 0; o < 5; ++o) out[s * 5 + o] = acc[o] + s_b[o];
}

extern "C" void kernel_launch(void* const* d_in, const int* in_sizes, int n_in,
                              void* d_out, int out_size, void* d_ws, size_t ws_size,
                              hipStream_t stream) {
  const float* x    = (const float*)d_in[0];
  const float* gso  = (const float*)d_in[1];
  const float* w_c1 = (const float*)d_in[2];
  const float* b_c1 = (const float*)d_in[3];
  const float* g_b1 = (const float*)d_in[4];
  const float* e_b1 = (const float*)d_in[5];
  const float* w_c2 = (const float*)d_in[6];
  const float* b_c2 = (const float*)d_in[7];
  const float* g_b2 = (const float*)d_in[8];
  const float* e_b2 = (const float*)d_in[9];
  const float* w_c3 = (const float*)d_in[10];
  const float* b_c3 = (const float*)d_in[11];
  const float* g_b3 = (const float*)d_in[12];
  const float* e_b3 = (const float*)d_in[13];
  const float* w_fc = (const float*)d_in[14];
  const float* b_fc = (const float*)d_in[15];
  const float* w_g1 = (const float*)d_in[16];
  const float* b_g1 = (const float*)d_in[17];
  const float* w_g2 = (const float*)d_in[18];
  const float* b_g2 = (const float*)d_in[19];
  const float* w_o  = (const float*)d_in[20];
  const float* b_o  = (const float*)d_in[21];
  float* out = (float*)d_out;
  float* W = (float*)d_ws;

  // workspace layout (floats), with reuse:
  float* c1   = W;               // 16384*512  = 8,388,608
  float* c2   = W + 8388608;     // 16384*256  = 4,194,304
  float* c3   = W + 12582912;    // 16384*128  = 2,097,152   (ws = 58.7 MB total)
  float* feat = W;               // reuse c1 region (dead after conv2)
  float* tmp1 = W + 2097152;
  float* hg1  = W + 4194304;
  float* tmp2 = W + 6291456;
  float* hg2  = W + 8388608;     // reuse c2 region (dead after conv3)
  float* ahat = W + 10485760;    // 256*64*64 = 1,048,576

  conv1_kernel<<<16384, 256, 0, stream>>>(x, w_c1, b_c1, g_b1, e_b1, c1);
  conv2_kernel<<<4096, 256, 0, stream>>>(c1, w_c2, b_c2, g_b2, e_b2, c2);
  conv3_kernel<<<2048, 256, 0, stream>>>(c2, w_c3, b_c3, g_b3, e_b3, c3);
  ahat_kernel<<<256, 256, 0, stream>>>(gso, ahat);
  gemm128_kernel<<<1024, 256, 0, stream>>>(c3, w_fc, b_fc, feat, 1);
  gemm128_kernel<<<1024, 256, 0, stream>>>(feat, w_g1, nullptr, tmp1, 0);
  agg_kernel<<<dim3(256, 2), 256, 0, stream>>>(ahat, tmp1, b_g1, hg1);
  gemm128_kernel<<<1024, 256, 0, stream>>>(hg1, w_g2, nullptr, tmp2, 0);
  agg_kernel<<<dim3(256, 2), 256, 0, stream>>>(ahat, tmp2, b_g2, hg2);
  head_kernel<<<64, 256, 0, stream>>>(hg2, w_o, b_o, out);
}

// Round 2
// 303.329 us; speedup vs baseline: 1.7344x; 1.7344x over previous
//
#include <hip/hip_runtime.h>
#include <math.h>

// Net_19335942767008 round 2: convs -> bf16 MFMA implicit GEMM (channel-last,
// tap-major K), FC/GCN stay fp32. B=256,N=64 -> S=16384 samples.

typedef __attribute__((ext_vector_type(8))) short bf16x8;
typedef __attribute__((ext_vector_type(4))) float f32x4;

__device__ __forceinline__ short f2bf(float f) {
  union { float f; unsigned u; } v; v.f = f;
  unsigned r = v.u + 0x7fffu + ((v.u >> 16) & 1u);
  return (short)(r >> 16);
}

// ---------- prep: x [S,3,8,8] f32 -> x4 [S,10,10,4] bf16 zero-padded ----------
__global__ __launch_bounds__(256) void prep_x4(const float* __restrict__ x,
                                               short* __restrict__ x4) {
  int c = blockIdx.x * 256 + threadIdx.x;  // 16384*100 cells
  int s = c / 100, cell = c - s * 100;
  int y = cell / 10, xx = cell - y * 10;
  int yy = y - 1, xc = xx - 1;
  ushort4 o = {0, 0, 0, 0};
  if ((unsigned)yy < 8u && (unsigned)xc < 8u) {
    const float* p = x + s * 192 + yy * 8 + xc;
    o.x = (unsigned short)f2bf(p[0]);
    o.y = (unsigned short)f2bf(p[64]);
    o.z = (unsigned short)f2bf(p[128]);
  }
  *(ushort4*)(x4 + c * 4) = o;
}

// ---------- weight packs ----------
__global__ __launch_bounds__(256) void pack1(const float* __restrict__ w,
                                             short* __restrict__ B1) {
  int idx = blockIdx.x * 256 + threadIdx.x;  // 32*64
  if (idx >= 2048) return;
  int oc = idx >> 6, k = idx & 63;
  int t = k >> 2, ic = k & 3;
  float v = (t < 9 && ic < 3) ? w[(oc * 3 + ic) * 9 + t] : 0.0f;
  B1[idx] = f2bf(v);
}

// Bp[oc][t][ic] = w[oc][ic][t]
__global__ __launch_bounds__(256) void pack_tmaj(const float* __restrict__ w,
                                                 short* __restrict__ Bp,
                                                 int IC, int total) {
  int idx = blockIdx.x * 256 + threadIdx.x;
  if (idx >= total) return;
  int ic9 = IC * 9;
  int oc = idx / ic9;
  int r = idx - oc * ic9;
  int t = r / IC;
  int ic = r - t * IC;
  Bp[idx] = f2bf(w[(oc * IC + ic) * 9 + t]);
}

// ---------- conv1 MFMA: x4 -> c1 [S,4,4,32] bf16 (pooled, unpadded) ----------
__global__ __launch_bounds__(256) void conv1_mfma(
    const short* __restrict__ x4, const short* __restrict__ B1,
    const float* __restrict__ bias, const float* __restrict__ g,
    const float* __restrict__ be, short* __restrict__ c1) {
  const int lane = threadIdx.x & 63;
  const int wid = blockIdx.x * 4 + (threadIdx.x >> 6);
  const int col = lane & 15, quad = lane >> 4;
  bf16x8 Bf[2][2];
#pragma unroll
  for (int nt = 0; nt < 2; ++nt)
#pragma unroll
    for (int ks = 0; ks < 2; ++ks)
      Bf[nt][ks] = *(const bf16x8*)(B1 + (nt * 16 + col) * 64 + ks * 32 + quad * 8);
  float Abn[2], Cbn[2];
#pragma unroll
  for (int nt = 0; nt < 2; ++nt) {
    int oc = nt * 16 + col;
    float a = g[oc] * rsqrtf(1.0f + 1e-5f);
    Abn[nt] = a;
    Cbn[nt] = fmaf(bias[oc], a, be[oc]);
  }
  const int t0 = 2 * quad, t1 = t0 + 1;
  const int ky0 = t0 / 3, kx0 = t0 - 3 * (t0 / 3);
  const int ky1 = t1 / 3, kx1 = t1 - 3 * (t1 / 3);
  const int m = lane & 15;
  const int pl = m >> 2, sub = m & 3;
  const int dy = sub >> 1, dx = sub & 1;
  const uint2 z2 = {0u, 0u};
#pragma unroll 1
  for (int si = 0; si < 8; ++si) {
    const int s = wid * 8 + si;
    const short* xb = x4 + s * 400;
#pragma unroll
    for (int tile = 0; tile < 4; ++tile) {
      const int pi = tile * 4 + pl;
      const int py = pi >> 2, px = pi & 3;
      const int cy = 2 * py + dy, cx = 2 * px + dx;
      union { bf16x8 v; uint2 u[2]; } a0, a1;
      a0.u[0] = *(const uint2*)(xb + ((cy + ky0) * 10 + cx + kx0) * 4);
      a0.u[1] = *(const uint2*)(xb + ((cy + ky1) * 10 + cx + kx1) * 4);
      uint2 u8 = *(const uint2*)(xb + ((cy + 2) * 10 + cx + 2) * 4);
      a1.u[0] = (quad == 0) ? u8 : z2;
      a1.u[1] = z2;
      f32x4 acc0 = {0, 0, 0, 0}, acc1 = {0, 0, 0, 0};
      acc0 = __builtin_amdgcn_mfma_f32_16x16x32_bf16(a0.v, Bf[0][0], acc0, 0, 0, 0);
      acc0 = __builtin_amdgcn_mfma_f32_16x16x32_bf16(a1.v, Bf[0][1], acc0, 0, 0, 0);
      acc1 = __builtin_amdgcn_mfma_f32_16x16x32_bf16(a0.v, Bf[1][0], acc1, 0, 0, 0);
      acc1 = __builtin_amdgcn_mfma_f32_16x16x32_bf16(a1.v, Bf[1][1], acc1, 0, 0, 0);
      const int piq = tile * 4 + quad;  // pooled pos held by this lane (C rows)
#pragma unroll
      for (int nt = 0; nt < 2; ++nt) {
        f32x4 acc = nt ? acc1 : acc0;
        float p0 = fmaf(acc[0], Abn[nt], Cbn[nt]);
        float p1 = fmaf(acc[1], Abn[nt], Cbn[nt]);
        float p2 = fmaf(acc[2], Abn[nt], Cbn[nt]);
        float p3 = fmaf(acc[3], Abn[nt], Cbn[nt]);
        float mx = fmaxf(fmaxf(fmaxf(p0, p1), fmaxf(p2, p3)), 0.0f);
        c1[s * 512 + piq * 32 + nt * 16 + col] = f2bf(mx);
      }
    }
  }
}

// ---------- conv2 MFMA: c1 [S,4,4,32] -> c2p [S,4,4,64] bf16 padded ----------
__global__ __launch_bounds__(256, 2) void conv2_mfma(
    const short* __restrict__ c1, const short* __restrict__ B2,
    const float* __restrict__ bias, const float* __restrict__ g,
    const float* __restrict__ be, short* __restrict__ c2p) {
  const int lane = threadIdx.x & 63;
  const int wid = blockIdx.x * 4 + (threadIdx.x >> 6);
  const int col = lane & 15, quad = lane >> 4;
  bf16x8 Bf[4][9];
#pragma unroll
  for (int nt = 0; nt < 4; ++nt)
#pragma unroll
    for (int t = 0; t < 9; ++t)
      Bf[nt][t] = *(const bf16x8*)(B2 + (nt * 16 + col) * 288 + t * 32 + quad * 8);
  float Abn[4], Cbn[4];
#pragma unroll
  for (int nt = 0; nt < 4; ++nt) {
    int oc = nt * 16 + col;
    float a = g[oc] * rsqrtf(1.0f + 1e-5f);
    Abn[nt] = a;
    Cbn[nt] = fmaf(bias[oc], a, be[oc]);
  }
  const int m = lane & 15;
  const int q2 = m >> 2, sub = m & 3;
  const int cy = 2 * (q2 >> 1) + (sub >> 1);
  const int cx = 2 * (q2 & 1) + (sub & 1);
  int off[9];
  bool valid[9];
#pragma unroll
  for (int t = 0; t < 9; ++t) {
    int ky = t / 3, kx = t - 3 * (t / 3);
    int yy = cy + ky - 1, xx = cx + kx - 1;
    valid[t] = ((unsigned)yy < 4u) && ((unsigned)xx < 4u);
    int yc = min(max(yy, 0), 3), xc = min(max(xx, 0), 3);
    off[t] = (yc * 4 + xc) * 32 + quad * 8;
  }
  const int outcell = (1 + (quad >> 1)) * 4 + 1 + (quad & 1);
  const bf16x8 zf = {0, 0, 0, 0, 0, 0, 0, 0};
#pragma unroll 1
  for (int si = 0; si < 8; ++si) {
    const int s = wid * 8 + si;
    const short* ib = c1 + s * 512;
    f32x4 acc[4];
#pragma unroll
    for (int nt = 0; nt < 4; ++nt) acc[nt] = (f32x4){0, 0, 0, 0};
#pragma unroll
    for (int t = 0; t < 9; ++t) {
      bf16x8 a = *(const bf16x8*)(ib + off[t]);
      if (!valid[t]) a = zf;
#pragma unroll
      for (int nt = 0; nt < 4; ++nt)
        acc[nt] = __builtin_amdgcn_mfma_f32_16x16x32_bf16(a, Bf[nt][t], acc[nt], 0, 0, 0);
    }
    short* ob = c2p + s * 1024;
#pragma unroll
    for (int nt = 0; nt < 4; ++nt) {
      float p0 = fmaf(acc[nt][0], Abn[nt], Cbn[nt]);
      float p1 = fmaf(acc[nt][1], Abn[nt], Cbn[nt]);
      float p2 = fmaf(acc[nt][2], Abn[nt], Cbn[nt]);
      float p3 = fmaf(acc[nt][3], Abn[nt], Cbn[nt]);
      float mx = fmaxf(fmaxf(fmaxf(p0, p1), fmaxf(p2, p3)), 0.0f);
      ob[outcell * 64 + nt * 16 + col] = f2bf(mx);
    }
    // border zeros: 12 cells x 128 B
    {
      int ci = lane >> 3;
      int cell = (ci < 4) ? ci : ci + 8;  // rows 0 and 3
      *(uint4*)(ob + cell * 64 + (lane & 7) * 8) = (uint4){0, 0, 0, 0};
      if (lane < 32) {
        int cc = lane >> 3;  // 0..3 -> cells 4,7,8,11
        int cell2 = 4 + (cc & 1) * 3 + ((cc >> 1) & 1) * 4;
        *(uint4*)(ob + cell2 * 64 + (lane & 7) * 8) = (uint4){0, 0, 0, 0};
      }
    }
  }
}

// ---------- conv3 MFMA: c2p -> c3 [S,128] f32 (pooled) ----------
__global__ __launch_bounds__(256) void conv3_mfma(
    const short* __restrict__ c2p, const short* __restrict__ B3,
    const float* __restrict__ bias, const float* __restrict__ g,
    const float* __restrict__ be, float* __restrict__ c3) {
  __shared__ short sB[32 * 584];  // 32 oc rows, K=576, +8 pad
  const int tid = threadIdx.x;
  const int ngroup = blockIdx.x & 3;
  const int mchunk = blockIdx.x >> 2;
#pragma unroll
  for (int it = 0; it < 9; ++it) {
    int cidx = it * 256 + tid;  // 2304 chunks of 8 bf16
    int row = cidx / 72, seg = cidx - row * 72;
    *(bf16x8*)(sB + row * 584 + seg * 8) =
        *(const bf16x8*)(B3 + (ngroup * 32 + row) * 576 + seg * 8);
  }
  __syncthreads();
  const int lane = tid & 63, w = tid >> 6;
  const int col = lane & 15, quad = lane >> 4;
  const int m = lane & 15;
  const int cp = m & 3, sl = m >> 2;
  const int cy = cp >> 1, cx = cp & 1;
  int aoff[18];
#pragma unroll
  for (int ks = 0; ks < 18; ++ks) {
    int t = ks >> 1;
    int ky = t / 3, kx = t - 3 * (t / 3);
    aoff[ks] = ((cy + ky) * 4 + cx + kx) * 64 + (ks & 1) * 32 + quad * 8;
  }
  const int s0 = (mchunk * 16 + w * 4) * 4;
  int sb[4];
#pragma unroll
  for (int mt = 0; mt < 4; ++mt) sb[mt] = (s0 + mt * 4 + sl) * 1024;
  const int nB0 = col * 584 + quad * 8;
  const int nB1 = (16 + col) * 584 + quad * 8;
  f32x4 acc[4][2];
#pragma unroll
  for (int mt = 0; mt < 4; ++mt)
#pragma unroll
    for (int nt = 0; nt < 2; ++nt) acc[mt][nt] = (f32x4){0, 0, 0, 0};
#pragma unroll
  for (int ks = 0; ks < 18; ++ks) {
    bf16x8 b0 = *(const bf16x8*)(sB + nB0 + ks * 32);
    bf16x8 b1 = *(const bf16x8*)(sB + nB1 + ks * 32);
#pragma unroll
    for (int mt = 0; mt < 4; ++mt) {
      bf16x8 a = *(const bf16x8*)(c2p + sb[mt] + aoff[ks]);
      acc[mt][0] = __builtin_amdgcn_mfma_f32_16x16x32_bf16(a, b0, acc[mt][0], 0, 0, 0);
      acc[mt][1] = __builtin_amdgcn_mfma_f32_16x16x32_bf16(a, b1, acc[mt][1], 0, 0, 0);
    }
  }
  float Abn[2], Cbn[2];
#pragma unroll
  for (int nt = 0; nt < 2; ++nt) {
    int oc = ngroup * 32 + nt * 16 + col;
    float a = g[oc] * rsqrtf(1.0f + 1e-5f);
    Abn[nt] = a;
    Cbn[nt] = fmaf(bias[oc], a, be[oc]);
  }
#pragma unroll
  for (int mt = 0; mt < 4; ++mt) {
    int sample = s0 + mt * 4 + quad;  // C rows: sl == quad
#pragma unroll
    for (int nt = 0; nt < 2; ++nt) {
      float p0 = fmaf(acc[mt][nt][0], Abn[nt], Cbn[nt]);
      float p1 = fmaf(acc[mt][nt][1], Abn[nt], Cbn[nt]);
      float p2 = fmaf(acc[mt][nt][2], Abn[nt], Cbn[nt]);
      float p3 = fmaf(acc[mt][nt][3], Abn[nt], Cbn[nt]);
      float mx = fmaxf(fmaxf(fmaxf(p0, p1), fmaxf(p2, p3)), 0.0f);
      c3[sample * 128 + ngroup * 32 + nt * 16 + col] = mx;
    }
  }
}

// ---------- ahat: gso[b] + I, sym-normalized ----------
__global__ __launch_bounds__(256) void ahat_kernel(
    const float* __restrict__ gso, float* __restrict__ ahat) {
  __shared__ float s_a[4096];
  __shared__ float s_d[64];
  const int bb = blockIdx.x;
  const int tid = threadIdx.x;
  for (int i = tid; i < 4096; i += 256) {
    const int r = i >> 6, c = i & 63;
    s_a[i] = gso[bb * 4096 + i] + (r == c ? 1.0f : 0.0f);
  }
  __syncthreads();
  if (tid < 64) {
    float sum = 0.0f;
    for (int j = 0; j < 64; ++j) sum += s_a[j * 64 + tid];
    s_d[tid] = rsqrtf(sum);
  }
  __syncthreads();
  for (int i = tid; i < 4096; i += 256) {
    const int r = i >> 6, c = i & 63;
    ahat[bb * 4096 + i] = s_d[r] * s_a[i] * s_d[c];
  }
}

// ---------- X[M,128] @ W[128,128]^T (+bias, relu), fp32 ----------
__global__ __launch_bounds__(256) void gemm128_kernel(
    const float* __restrict__ X, const float* __restrict__ Wt,
    const float* __restrict__ bias, float* __restrict__ out, int relu) {
  __shared__ float s_x[16 * 128];
  __shared__ float s_w[32 * 129];
  const int tid = threadIdx.x;
  const int n = tid & 127;
  const int sr = tid >> 7;
  const int s0 = blockIdx.x * 16;
  for (int i = tid; i < 2048; i += 256) s_x[i] = X[s0 * 128 + i];
  float acc[8];
  for (int r = 0; r < 8; ++r) acc[r] = 0.0f;
  for (int chunk = 0; chunk < 4; ++chunk) {
    __syncthreads();
    for (int i = tid; i < 4096; i += 256) {
      const int nw = i >> 5;
      const int kc = i & 31;
      s_w[kc * 129 + nw] = Wt[nw * 128 + chunk * 32 + kc];
    }
    __syncthreads();
    for (int kc = 0; kc < 32; ++kc) {
      const float wv = s_w[kc * 129 + n];
      const int k = chunk * 32 + kc;
      for (int r = 0; r < 8; ++r)
        acc[r] = fmaf(wv, s_x[(sr + 2 * r) * 128 + k], acc[r]);
    }
  }
  const float bv = bias ? bias[n] : 0.0f;
  for (int r = 0; r < 8; ++r) {
    float v = acc[r] + bv;
    if (relu) v = fmaxf(v, 0.0f);
    out[(s0 + sr + 2 * r) * 128 + n] = v;
  }
}

// ---------- agg: out[b] = relu(ahat[b] @ T[b] + bias) ----------
__global__ __launch_bounds__(256) void agg_kernel(
    const float* __restrict__ ahat, const float* __restrict__ T,
    const float* __restrict__ bias, float* __restrict__ out) {
  __shared__ float s_a[4096];
  __shared__ float s_t[4096];
  const int bb = blockIdx.x;
  const int half = blockIdx.y;
  const int tid = threadIdx.x;
  const int c = tid & 63;
  const int f = (half << 6) + c;
  const int ib = tid >> 6;
  for (int i = tid; i < 4096; i += 256) s_a[i] = ahat[bb * 4096 + i];
  for (int i = tid; i < 4096; i += 256) {
    const int j = i >> 6, cc = i & 63;
    s_t[i] = T[bb * 8192 + j * 128 + (half << 6) + cc];
  }
  __syncthreads();
  float acc[16];
  for (int r = 0; r < 16; ++r) acc[r] = 0.0f;
  for (int j = 0; j < 64; ++j) {
    const float tv = s_t[j * 64 + c];
    for (int r = 0; r < 16; ++r)
      acc[r] = fmaf(s_a[(ib + 4 * r) * 64 + j], tv, acc[r]);
  }
  const float bv = bias[f];
  for (int r = 0; r < 16; ++r) {
    const int i = ib + 4 * r;
    out[bb * 8192 + i * 128 + f] = fmaxf(acc[r] + bv, 0.0f);
  }
}

// ---------- head: [S,128] @ w_out[5,128]^T + b ----------
__global__ __launch_bounds__(256) void head_kernel(
    const float* __restrict__ H, const float* __restrict__ Wo,
    const float* __restrict__ bo, float* __restrict__ out) {
  __shared__ float s_w[640];
  __shared__ float s_b[5];
  const int tid = threadIdx.x;
  for (int i = tid; i < 640; i += 256) s_w[i] = Wo[i];
  if (tid < 5) s_b[tid] = bo[tid];
  __syncthreads();
  const int s = blockIdx.x * 256 + tid;
  const float4* h4 = (const float4*)(H + s * 128);
  float acc[5] = {0.f, 0.f, 0.f, 0.f, 0.f};
  for (int k4 = 0; k4 < 32; ++k4) {
    const float4 h = h4[k4];
    for (int o = 0; o < 5; ++o) {
      acc[o] = fmaf(h.x, s_w[o * 128 + k4 * 4 + 0], acc[o]);
      acc[o] = fmaf(h.y, s_w[o * 128 + k4 * 4 + 1], acc[o]);
      acc[o] = fmaf(h.z, s_w[o * 128 + k4 * 4 + 2], acc[o]);
      acc[o] = fmaf(h.w, s_w[o * 128 + k4 * 4 + 3], acc[o]);
    }
  }
  for (int o = 0; o < 5; ++o) out[s * 5 + o] = acc[o] + s_b[o];
}

extern "C" void kernel_launch(void* const* d_in, const int* in_sizes, int n_in,
                              void* d_out, int out_size, void* d_ws, size_t ws_size,
                              hipStream_t stream) {
  const float* x    = (const float*)d_in[0];
  const float* gso  = (const float*)d_in[1];
  const float* w_c1 = (const float*)d_in[2];
  const float* b_c1 = (const float*)d_in[3];
  const float* g_b1 = (const float*)d_in[4];
  const float* e_b1 = (const float*)d_in[5];
  const float* w_c2 = (const float*)d_in[6];
  const float* b_c2 = (const float*)d_in[7];
  const float* g_b2 = (const float*)d_in[8];
  const float* e_b2 = (const float*)d_in[9];
  const float* w_c3 = (const float*)d_in[10];
  const float* b_c3 = (const float*)d_in[11];
  const float* g_b3 = (const float*)d_in[12];
  const float* e_b3 = (const float*)d_in[13];
  const float* w_fc = (const float*)d_in[14];
  const float* b_fc = (const float*)d_in[15];
  const float* w_g1 = (const float*)d_in[16];
  const float* b_g1 = (const float*)d_in[17];
  const float* w_g2 = (const float*)d_in[18];
  const float* b_g2 = (const float*)d_in[19];
  const float* w_o  = (const float*)d_in[20];
  const float* b_o  = (const float*)d_in[21];
  float* out = (float*)d_out;
  char* ws = (char*)d_ws;

  // workspace layout (bytes), overlapped by lifetime; peak 54.72 MB
  short* c1   = (short*)(ws + 0);          // 16,777,216 (dead after conv2)
  short* x4   = (short*)(ws + 16777216);   // 13,107,200 (dead after conv1)
  short* c2p  = (short*)(ws + 16777216);   // 33,554,432 (overlays x4; dead after conv3)
  float* c3   = (float*)(ws + 0);          // 8,388,608 (overlays c1)
  float* feat = (float*)(ws + 8388608);
  float* tmp1 = (float*)(ws + 16777216);   // overlays c2p (dead by then)
  float* hg1  = (float*)(ws + 25165824);
  float* tmp2 = (float*)(ws + 33554432);
  float* hg2  = (float*)(ws + 41943040);
  float* ahat = (float*)(ws + 50331648);   // 4,194,304
  short* B1   = (short*)(ws + 54525952);   // 4 KB
  short* B2   = (short*)(ws + 54530048);   // 36,864
  short* B3   = (short*)(ws + 54566912);   // 147,456

  pack1<<<8, 256, 0, stream>>>(w_c1, B1);
  pack_tmaj<<<72, 256, 0, stream>>>(w_c2, B2, 32, 18432);
  pack_tmaj<<<288, 256, 0, stream>>>(w_c3, B3, 64, 73728);
  prep_x4<<<6400, 256, 0, stream>>>(x, x4);
  conv1_mfma<<<512, 256, 0, stream>>>(x4, B1, b_c1, g_b1, e_b1, c1);
  conv2_mfma<<<512, 256, 0, stream>>>(c1, B2, b_c2, g_b2, e_b2, c2p);
  conv3_mfma<<<1024, 256, 0, stream>>>(c2p, B3, b_c3, g_b3, e_b3, c3);
  ahat_kernel<<<256, 256, 0, stream>>>(gso, ahat);
  gemm128_kernel<<<1024, 256, 0, stream>>>(c3, w_fc, b_fc, feat, 1);
  gemm128_kernel<<<1024, 256, 0, stream>>>(feat, w_g1, nullptr, tmp1, 0);
  agg_kernel<<<dim3(256, 2), 256, 0, stream>>>(ahat, tmp1, b_g1, hg1);
  gemm128_kernel<<<1024, 256, 0, stream>>>(hg1, w_g2, nullptr, tmp2, 0);
  agg_kernel<<<dim3(256, 2), 256, 0, stream>>>(ahat, tmp2, b_g2, hg2);
  head_kernel<<<64, 256, 0, stream>>>(hg2, w_o, b_o, out);
}

// Round 4
// 247.190 us; speedup vs baseline: 2.1283x; 1.2271x over previous
//
#include <hip/hip_runtime.h>
#include <math.h>

// Net_19335942767008 round 4: same validated math as round 3, but workspace has
// ZERO aliasing (epoch-idempotent: every buffer fully rewritten by the same
// producer every call) to fix post-timing divergence. conv1 reads raw fp32 x
// directly (padded x4 staging dropped to fit the no-alias layout in ws).

typedef __attribute__((ext_vector_type(8))) short bf16x8;
typedef __attribute__((ext_vector_type(4))) float f32x4;

__device__ __forceinline__ short f2bf(float f) {
  union { float f; unsigned u; } v; v.f = f;
  unsigned r = v.u + 0x7fffu + ((v.u >> 16) & 1u);
  return (short)(r >> 16);
}
__device__ __forceinline__ float bf2f(unsigned short u) {
  union { unsigned u; float f; } v; v.u = ((unsigned)u) << 16;
  return v.f;
}

// ---------- weight packs ----------
__global__ __launch_bounds__(256) void pack1(const float* __restrict__ w,
                                             short* __restrict__ B1) {
  int idx = blockIdx.x * 256 + threadIdx.x;  // 32*64
  if (idx >= 2048) return;
  int oc = idx >> 6, k = idx & 63;
  int t = k >> 2, ic = k & 3;
  float v = (t < 9 && ic < 3) ? w[(oc * 3 + ic) * 9 + t] : 0.0f;
  B1[idx] = f2bf(v);
}

// Bp[oc][t][ic] = w[oc][ic][t]
__global__ __launch_bounds__(256) void pack_tmaj(const float* __restrict__ w,
                                                 short* __restrict__ Bp,
                                                 int IC, int total) {
  int idx = blockIdx.x * 256 + threadIdx.x;
  if (idx >= total) return;
  int ic9 = IC * 9;
  int oc = idx / ic9;
  int r = idx - oc * ic9;
  int t = r / IC;
  int ic = r - t * IC;
  Bp[idx] = f2bf(w[(oc * IC + ic) * 9 + t]);
}

__global__ __launch_bounds__(256) void pack_dense(const float* __restrict__ w,
                                                  short* __restrict__ o, int total) {
  int idx = blockIdx.x * 256 + threadIdx.x;
  if (idx < total) o[idx] = f2bf(w[idx]);
}

// ---------- conv1 MFMA: x [S,3,8,8] f32 -> c1 [S,4,4,32] bf16 (pooled) ----------
__global__ __launch_bounds__(256) void conv1_mfma(
    const float* __restrict__ x, const short* __restrict__ B1,
    const float* __restrict__ bias, const float* __restrict__ g,
    const float* __restrict__ be, short* __restrict__ c1) {
  const int lane = threadIdx.x & 63;
  const int wid = blockIdx.x * 4 + (threadIdx.x >> 6);
  const int col = lane & 15, quad = lane >> 4;
  bf16x8 Bf[2][2];
#pragma unroll
  for (int nt = 0; nt < 2; ++nt)
#pragma unroll
    for (int ks = 0; ks < 2; ++ks)
      Bf[nt][ks] = *(const bf16x8*)(B1 + (nt * 16 + col) * 64 + ks * 32 + quad * 8);
  float Abn[2], Cbn[2];
#pragma unroll
  for (int nt = 0; nt < 2; ++nt) {
    int oc = nt * 16 + col;
    float a = g[oc] * rsqrtf(1.0f + 1e-5f);
    Abn[nt] = a;
    Cbn[nt] = fmaf(bias[oc], a, be[oc]);
  }
  const int t0 = 2 * quad, t1 = t0 + 1;
  const int ky0 = t0 / 3, kx0 = t0 - 3 * (t0 / 3);
  const int ky1 = t1 / 3, kx1 = t1 - 3 * (t1 / 3);
  const int m = lane & 15;
  const int pl = m >> 2, sub = m & 3;
  const int dy = sub >> 1, dx = sub & 1;
#pragma unroll 1
  for (int si = 0; si < 8; ++si) {
    const int s = wid * 8 + si;
    const float* xb = x + s * 192;
#pragma unroll
    for (int tile = 0; tile < 4; ++tile) {
      const int pi = tile * 4 + pl;
      const int py = pi >> 2, px = pi & 3;
      const int cy = 2 * py + dy, cx = 2 * px + dx;
      union { bf16x8 v; short sh[8]; } a0, a1;
      {  // tap t0 -> k-slots 0..3 of this quad's chunk
        int yy = cy + ky0 - 1, xx = cx + kx0 - 1;
        bool vd = ((unsigned)yy < 8u) && ((unsigned)xx < 8u);
        int idx = vd ? (yy * 8 + xx) : 0;
        a0.sh[0] = vd ? f2bf(xb[idx]) : (short)0;
        a0.sh[1] = vd ? f2bf(xb[64 + idx]) : (short)0;
        a0.sh[2] = vd ? f2bf(xb[128 + idx]) : (short)0;
        a0.sh[3] = 0;
      }
      {  // tap t1 -> k-slots 4..7
        int yy = cy + ky1 - 1, xx = cx + kx1 - 1;
        bool vd = ((unsigned)yy < 8u) && ((unsigned)xx < 8u);
        int idx = vd ? (yy * 8 + xx) : 0;
        a0.sh[4] = vd ? f2bf(xb[idx]) : (short)0;
        a0.sh[5] = vd ? f2bf(xb[64 + idx]) : (short)0;
        a0.sh[6] = vd ? f2bf(xb[128 + idx]) : (short)0;
        a0.sh[7] = 0;
      }
      {  // tap t8 (ky=kx=2): only quad 0 of second MFMA (k=32..35)
        int yy = cy + 1, xx = cx + 1;
        bool vd = (quad == 0) && (yy < 8) && (xx < 8);
        int idx = vd ? (yy * 8 + xx) : 0;
        a1.sh[0] = vd ? f2bf(xb[idx]) : (short)0;
        a1.sh[1] = vd ? f2bf(xb[64 + idx]) : (short)0;
        a1.sh[2] = vd ? f2bf(xb[128 + idx]) : (short)0;
        a1.sh[3] = 0;
        a1.sh[4] = 0; a1.sh[5] = 0; a1.sh[6] = 0; a1.sh[7] = 0;
      }
      f32x4 acc0 = {0, 0, 0, 0}, acc1 = {0, 0, 0, 0};
      acc0 = __builtin_amdgcn_mfma_f32_16x16x32_bf16(a0.v, Bf[0][0], acc0, 0, 0, 0);
      acc0 = __builtin_amdgcn_mfma_f32_16x16x32_bf16(a1.v, Bf[0][1], acc0, 0, 0, 0);
      acc1 = __builtin_amdgcn_mfma_f32_16x16x32_bf16(a0.v, Bf[1][0], acc1, 0, 0, 0);
      acc1 = __builtin_amdgcn_mfma_f32_16x16x32_bf16(a1.v, Bf[1][1], acc1, 0, 0, 0);
      const int piq = tile * 4 + quad;
#pragma unroll
      for (int nt = 0; nt < 2; ++nt) {
        f32x4 acc = nt ? acc1 : acc0;
        float p0 = fmaf(acc[0], Abn[nt], Cbn[nt]);
        float p1 = fmaf(acc[1], Abn[nt], Cbn[nt]);
        float p2 = fmaf(acc[2], Abn[nt], Cbn[nt]);
        float p3 = fmaf(acc[3], Abn[nt], Cbn[nt]);
        float mx = fmaxf(fmaxf(fmaxf(p0, p1), fmaxf(p2, p3)), 0.0f);
        c1[s * 512 + piq * 32 + nt * 16 + col] = f2bf(mx);
      }
    }
  }
}

// ---------- conv2 MFMA: c1 [S,4,4,32] -> c2 [S,2,2,64] bf16 ----------
__global__ __launch_bounds__(256, 2) void conv2_mfma(
    const short* __restrict__ c1, const short* __restrict__ B2,
    const float* __restrict__ bias, const float* __restrict__ g,
    const float* __restrict__ be, short* __restrict__ c2) {
  const int lane = threadIdx.x & 63;
  const int wid = blockIdx.x * 4 + (threadIdx.x >> 6);
  const int col = lane & 15, quad = lane >> 4;
  bf16x8 Bf[4][9];
#pragma unroll
  for (int nt = 0; nt < 4; ++nt)
#pragma unroll
    for (int t = 0; t < 9; ++t)
      Bf[nt][t] = *(const bf16x8*)(B2 + (nt * 16 + col) * 288 + t * 32 + quad * 8);
  float Abn[4], Cbn[4];
#pragma unroll
  for (int nt = 0; nt < 4; ++nt) {
    int oc = nt * 16 + col;
    float a = g[oc] * rsqrtf(1.0f + 1e-5f);
    Abn[nt] = a;
    Cbn[nt] = fmaf(bias[oc], a, be[oc]);
  }
  const int m = lane & 15;
  const int q2 = m >> 2, sub = m & 3;
  const int cy = 2 * (q2 >> 1) + (sub >> 1);
  const int cx = 2 * (q2 & 1) + (sub & 1);
  int off[9];
  bool valid[9];
#pragma unroll
  for (int t = 0; t < 9; ++t) {
    int ky = t / 3, kx = t - 3 * (t / 3);
    int yy = cy + ky - 1, xx = cx + kx - 1;
    valid[t] = ((unsigned)yy < 4u) && ((unsigned)xx < 4u);
    int yc = min(max(yy, 0), 3), xc = min(max(xx, 0), 3);
    off[t] = (yc * 4 + xc) * 32 + quad * 8;
  }
  const bf16x8 zf = {0, 0, 0, 0, 0, 0, 0, 0};
#pragma unroll 1
  for (int si = 0; si < 8; ++si) {
    const int s = wid * 8 + si;
    const short* ib = c1 + s * 512;
    f32x4 acc[4];
#pragma unroll
    for (int nt = 0; nt < 4; ++nt) acc[nt] = (f32x4){0, 0, 0, 0};
#pragma unroll
    for (int t = 0; t < 9; ++t) {
      bf16x8 a = *(const bf16x8*)(ib + off[t]);
      if (!valid[t]) a = zf;
#pragma unroll
      for (int nt = 0; nt < 4; ++nt)
        acc[nt] = __builtin_amdgcn_mfma_f32_16x16x32_bf16(a, Bf[nt][t], acc[nt], 0, 0, 0);
    }
    short* ob = c2 + s * 256;
#pragma unroll
    for (int nt = 0; nt < 4; ++nt) {
      float p0 = fmaf(acc[nt][0], Abn[nt], Cbn[nt]);
      float p1 = fmaf(acc[nt][1], Abn[nt], Cbn[nt]);
      float p2 = fmaf(acc[nt][2], Abn[nt], Cbn[nt]);
      float p3 = fmaf(acc[nt][3], Abn[nt], Cbn[nt]);
      float mx = fmaxf(fmaxf(fmaxf(p0, p1), fmaxf(p2, p3)), 0.0f);
      ob[quad * 64 + nt * 16 + col] = f2bf(mx);  // pooled cell == quad
    }
  }
}

// ---------- conv3 MFMA: c2 [S,2,2,64] -> c3 [S,128] bf16; A fetched ONCE ----------
__global__ __launch_bounds__(256) void conv3_mfma(
    const short* __restrict__ c2, const short* __restrict__ B3,
    const float* __restrict__ bias, const float* __restrict__ g,
    const float* __restrict__ be, short* __restrict__ c3) {
  __shared__ short sB[32 * 584];  // 32 oc rows x K=576, +8 pad
  const int tid = threadIdx.x;
  const int lane = tid & 63, w = tid >> 6;
  const int col = lane & 15, quad = lane >> 4;
  const int m = lane & 15;
  const int cp = m & 3, sl = m >> 2;
  const int cy = cp >> 1, cx = cp & 1;
  const int s = blockIdx.x * 16 + w * 4 + sl;
  const short* ib = c2 + s * 256;
  bf16x8 A[18];
  const bf16x8 zf = {0, 0, 0, 0, 0, 0, 0, 0};
#pragma unroll
  for (int ks = 0; ks < 18; ++ks) {
    int t = ks >> 1;
    int ky = t / 3, kx = t - 3 * (t / 3);
    int iy = cy + ky - 1, ix = cx + kx - 1;
    bool valid = ((unsigned)iy < 2u) && ((unsigned)ix < 2u);
    int iyc = min(max(iy, 0), 1), ixc = min(max(ix, 0), 1);
    bf16x8 a = *(const bf16x8*)(ib + (iyc * 2 + ixc) * 64 + (ks & 1) * 32 + quad * 8);
    A[ks] = valid ? a : zf;
  }
  f32x4 acc[8];
#pragma unroll
  for (int i = 0; i < 8; ++i) acc[i] = (f32x4){0, 0, 0, 0};
#pragma unroll
  for (int ng = 0; ng < 4; ++ng) {
    __syncthreads();
#pragma unroll
    for (int it = 0; it < 9; ++it) {
      int cidx = it * 256 + tid;
      int row = cidx / 72, seg = cidx - row * 72;
      *(bf16x8*)(sB + row * 584 + seg * 8) =
          *(const bf16x8*)(B3 + (ng * 32 + row) * 576 + seg * 8);
    }
    __syncthreads();
#pragma unroll
    for (int nt = 0; nt < 2; ++nt) {
      const int nB = (nt * 16 + col) * 584 + quad * 8;
#pragma unroll
      for (int ks = 0; ks < 18; ++ks) {
        bf16x8 b = *(const bf16x8*)(sB + nB + ks * 32);
        acc[ng * 2 + nt] =
            __builtin_amdgcn_mfma_f32_16x16x32_bf16(A[ks], b, acc[ng * 2 + nt], 0, 0, 0);
      }
    }
  }
  const int sample = blockIdx.x * 16 + w * 4 + quad;
#pragma unroll
  for (int i = 0; i < 8; ++i) {
    int oc = (i >> 1) * 32 + (i & 1) * 16 + col;
    float a = g[oc] * rsqrtf(1.0f + 1e-5f);
    float cc = fmaf(bias[oc], a, be[oc]);
    float p0 = fmaf(acc[i][0], a, cc);
    float p1 = fmaf(acc[i][1], a, cc);
    float p2 = fmaf(acc[i][2], a, cc);
    float p3 = fmaf(acc[i][3], a, cc);
    float mx = fmaxf(fmaxf(fmaxf(p0, p1), fmaxf(p2, p3)), 0.0f);
    c3[sample * 128 + oc] = f2bf(mx);
  }
}

// ---------- ahat: gso[b] + I, sym-normalized (fp32) ----------
__global__ __launch_bounds__(256) void ahat_kernel(
    const float* __restrict__ gso, float* __restrict__ ahat) {
  __shared__ float s_a[4096];
  __shared__ float s_d[64];
  const int bb = blockIdx.x;
  const int tid = threadIdx.x;
  for (int i = tid; i < 4096; i += 256) {
    const int r = i >> 6, c = i & 63;
    s_a[i] = gso[bb * 4096 + i] + (r == c ? 1.0f : 0.0f);
  }
  __syncthreads();
  if (tid < 64) {
    float sum = 0.0f;
    for (int j = 0; j < 64; ++j) sum += s_a[j * 64 + tid];
    s_d[tid] = rsqrtf(sum);
  }
  __syncthreads();
  for (int i = tid; i < 4096; i += 256) {
    const int r = i >> 6, c = i & 63;
    ahat[bb * 4096 + i] = s_d[r] * s_a[i] * s_d[c];
  }
}

// ---------- bf16 GEMM: X[M,128] @ Wb[128,128](row=n) -> out bf16 ----------
__global__ __launch_bounds__(256) void gemm_bf16(
    const short* __restrict__ X, const short* __restrict__ Wb,
    const float* __restrict__ bias, short* __restrict__ out, int relu) {
  __shared__ short sW[128 * 136];
  const int tid = threadIdx.x;
#pragma unroll
  for (int it = 0; it < 8; ++it) {
    int cidx = it * 256 + tid;
    int row = cidx >> 4, seg = cidx & 15;
    *(bf16x8*)(sW + row * 136 + seg * 8) = *(const bf16x8*)(Wb + row * 128 + seg * 8);
  }
  __syncthreads();
  const int lane = tid & 63, w = tid >> 6;
  const int col = lane & 15, quad = lane >> 4;
  const int sA = blockIdx.x * 64 + w * 16 + col;
  bf16x8 A[4];
#pragma unroll
  for (int ks = 0; ks < 4; ++ks)
    A[ks] = *(const bf16x8*)(X + sA * 128 + ks * 32 + quad * 8);
  f32x4 acc[8];
#pragma unroll
  for (int i = 0; i < 8; ++i) acc[i] = (f32x4){0, 0, 0, 0};
#pragma unroll
  for (int nt = 0; nt < 8; ++nt) {
    const int nB = (nt * 16 + col) * 136 + quad * 8;
#pragma unroll
    for (int ks = 0; ks < 4; ++ks) {
      bf16x8 b = *(const bf16x8*)(sW + nB + ks * 32);
      acc[nt] = __builtin_amdgcn_mfma_f32_16x16x32_bf16(A[ks], b, acc[nt], 0, 0, 0);
    }
  }
  const int so = blockIdx.x * 64 + w * 16 + quad * 4;
#pragma unroll
  for (int nt = 0; nt < 8; ++nt) {
    const int n = nt * 16 + col;
    const float bv = bias ? bias[n] : 0.0f;
#pragma unroll
    for (int reg = 0; reg < 4; ++reg) {
      float v = acc[nt][reg] + bv;
      if (relu) v = fmaxf(v, 0.0f);
      out[(so + reg) * 128 + n] = f2bf(v);
    }
  }
}

// ---------- agg: out[b] = relu(ahat[b] @ T[b] + bias); fp32 math, bf16 I/O ----------
__global__ __launch_bounds__(256) void agg_kernel(
    const float* __restrict__ ahat, const short* __restrict__ T,
    const float* __restrict__ bias, short* __restrict__ out) {
  __shared__ float s_a[4096];
  __shared__ float s_t[4096];
  const int bb = blockIdx.x;
  const int half = blockIdx.y;
  const int tid = threadIdx.x;
  const int c = tid & 63;
  const int f = (half << 6) + c;
  const int ib = tid >> 6;
  for (int i = tid; i < 4096; i += 256) s_a[i] = ahat[bb * 4096 + i];
  for (int i = tid; i < 4096; i += 256) {
    const int j = i >> 6, cc = i & 63;
    s_t[i] = bf2f((unsigned short)T[bb * 8192 + j * 128 + (half << 6) + cc]);
  }
  __syncthreads();
  float acc[16];
  for (int r = 0; r < 16; ++r) acc[r] = 0.0f;
  for (int j = 0; j < 64; ++j) {
    const float tv = s_t[j * 64 + c];
    for (int r = 0; r < 16; ++r)
      acc[r] = fmaf(s_a[(ib + 4 * r) * 64 + j], tv, acc[r]);
  }
  const float bv = bias[f];
  for (int r = 0; r < 16; ++r) {
    const int i = ib + 4 * r;
    out[bb * 8192 + i * 128 + f] = f2bf(fmaxf(acc[r] + bv, 0.0f));
  }
}

// ---------- head: [S,128]bf16 @ w_out[5,128]^T + b -> fp32 ----------
__global__ __launch_bounds__(256) void head_kernel(
    const short* __restrict__ H, const float* __restrict__ Wo,
    const float* __restrict__ bo, float* __restrict__ out) {
  __shared__ float s_w[640];
  __shared__ float s_b[5];
  const int tid = threadIdx.x;
  for (int i = tid; i < 640; i += 256) s_w[i] = Wo[i];
  if (tid < 5) s_b[tid] = bo[tid];
  __syncthreads();
  const int s = blockIdx.x * 256 + tid;
  float acc[5] = {0.f, 0.f, 0.f, 0.f, 0.f};
#pragma unroll
  for (int k8 = 0; k8 < 16; ++k8) {
    union { bf16x8 v; unsigned short u[8]; } h;
    h.v = *(const bf16x8*)(H + s * 128 + k8 * 8);
#pragma unroll
    for (int j = 0; j < 8; ++j) {
      float hv = bf2f(h.u[j]);
      for (int o = 0; o < 5; ++o)
        acc[o] = fmaf(hv, s_w[o * 128 + k8 * 8 + j], acc[o]);
    }
  }
  for (int o = 0; o < 5; ++o) out[s * 5 + o] = acc[o] + s_b[o];
}

extern "C" void kernel_launch(void* const* d_in, const int* in_sizes, int n_in,
                              void* d_out, int out_size, void* d_ws, size_t ws_size,
                              hipStream_t stream) {
  const float* x    = (const float*)d_in[0];
  const float* gso  = (const float*)d_in[1];
  const float* w_c1 = (const float*)d_in[2];
  const float* b_c1 = (const float*)d_in[3];
  const float* g_b1 = (const float*)d_in[4];
  const float* e_b1 = (const float*)d_in[5];
  const float* w_c2 = (const float*)d_in[6];
  const float* b_c2 = (const float*)d_in[7];
  const float* g_b2 = (const float*)d_in[8];
  const float* e_b2 = (const float*)d_in[9];
  const float* w_c3 = (const float*)d_in[10];
  const float* b_c3 = (const float*)d_in[11];
  const float* g_b3 = (const float*)d_in[12];
  const float* e_b3 = (const float*)d_in[13];
  const float* w_fc = (const float*)d_in[14];
  const float* b_fc = (const float*)d_in[15];
  const float* w_g1 = (const float*)d_in[16];
  const float* b_g1 = (const float*)d_in[17];
  const float* w_g2 = (const float*)d_in[18];
  const float* b_g2 = (const float*)d_in[19];
  const float* w_o  = (const float*)d_in[20];
  const float* b_o  = (const float*)d_in[21];
  float* out = (float*)d_out;
  char* ws = (char*)d_ws;

  // workspace layout (bytes) — NO ALIASING, total 54,812,672 (< proven 58.72 MB)
  short* c1   = (short*)(ws + 0);          // 16,777,216
  short* c2   = (short*)(ws + 16777216);   //  8,388,608
  short* c3   = (short*)(ws + 25165824);   //  4,194,304
  short* feat = (short*)(ws + 29360128);   //  4,194,304
  short* tmp1 = (short*)(ws + 33554432);   //  4,194,304
  short* hg1  = (short*)(ws + 37748736);   //  4,194,304
  short* tmp2 = (short*)(ws + 41943040);   //  4,194,304
  short* hg2  = (short*)(ws + 46137344);   //  4,194,304
  float* ahat = (float*)(ws + 50331648);   //  4,194,304
  short* B1   = (short*)(ws + 54525952);   //  4,096
  short* B2   = (short*)(ws + 54530048);   //  36,864
  short* B3   = (short*)(ws + 54566912);   //  147,456
  short* Wfc  = (short*)(ws + 54714368);   //  32,768
  short* Wg1  = (short*)(ws + 54747136);   //  32,768
  short* Wg2  = (short*)(ws + 54779904);   //  32,768

  pack1<<<8, 256, 0, stream>>>(w_c1, B1);
  pack_tmaj<<<72, 256, 0, stream>>>(w_c2, B2, 32, 18432);
  pack_tmaj<<<288, 256, 0, stream>>>(w_c3, B3, 64, 73728);
  pack_dense<<<64, 256, 0, stream>>>(w_fc, Wfc, 16384);
  pack_dense<<<64, 256, 0, stream>>>(w_g1, Wg1, 16384);
  pack_dense<<<64, 256, 0, stream>>>(w_g2, Wg2, 16384);
  conv1_mfma<<<512, 256, 0, stream>>>(x, B1, b_c1, g_b1, e_b1, c1);
  conv2_mfma<<<512, 256, 0, stream>>>(c1, B2, b_c2, g_b2, e_b2, c2);
  conv3_mfma<<<1024, 256, 0, stream>>>(c2, B3, b_c3, g_b3, e_b3, c3);
  ahat_kernel<<<256, 256, 0, stream>>>(gso, ahat);
  gemm_bf16<<<256, 256, 0, stream>>>(c3, Wfc, b_fc, feat, 1);
  gemm_bf16<<<256, 256, 0, stream>>>(feat, Wg1, nullptr, tmp1, 0);
  agg_kernel<<<dim3(256, 2), 256, 0, stream>>>(ahat, tmp1, b_g1, hg1);
  gemm_bf16<<<256, 256, 0, stream>>>(hg1, Wg2, nullptr, tmp2, 0);
  agg_kernel<<<dim3(256, 2), 256, 0, stream>>>(ahat, tmp2, b_g2, hg2);
  head_kernel<<<64, 256, 0, stream>>>(hg2, w_o, b_o, out);
}

// Round 5
// 219.424 us; speedup vs baseline: 2.3977x; 1.1265x over previous
//
#include <hip/hip_runtime.h>
#include <math.h>

// Net_19335942767008 round 5: conv1 rebuilt — padded bf16 frame staged in LDS
// (coalesced global reads, 3 LDS uint2 reads per tile), grid 512->2048.
// Everything else bit-identical to validated round 4. No workspace aliasing.

typedef __attribute__((ext_vector_type(8))) short bf16x8;
typedef __attribute__((ext_vector_type(4))) float f32x4;

__device__ __forceinline__ short f2bf(float f) {
  union { float f; unsigned u; } v; v.f = f;
  unsigned r = v.u + 0x7fffu + ((v.u >> 16) & 1u);
  return (short)(r >> 16);
}
__device__ __forceinline__ float bf2f(unsigned short u) {
  union { unsigned u; float f; } v; v.u = ((unsigned)u) << 16;
  return v.f;
}

// ---------- weight packs ----------
__global__ __launch_bounds__(256) void pack1(const float* __restrict__ w,
                                             short* __restrict__ B1) {
  int idx = blockIdx.x * 256 + threadIdx.x;  // 32*64
  if (idx >= 2048) return;
  int oc = idx >> 6, k = idx & 63;
  int t = k >> 2, ic = k & 3;
  float v = (t < 9 && ic < 3) ? w[(oc * 3 + ic) * 9 + t] : 0.0f;
  B1[idx] = f2bf(v);
}

// Bp[oc][t][ic] = w[oc][ic][t]
__global__ __launch_bounds__(256) void pack_tmaj(const float* __restrict__ w,
                                                 short* __restrict__ Bp,
                                                 int IC, int total) {
  int idx = blockIdx.x * 256 + threadIdx.x;
  if (idx >= total) return;
  int ic9 = IC * 9;
  int oc = idx / ic9;
  int r = idx - oc * ic9;
  int t = r / IC;
  int ic = r - t * IC;
  Bp[idx] = f2bf(w[(oc * IC + ic) * 9 + t]);
}

__global__ __launch_bounds__(256) void pack_dense(const float* __restrict__ w,
                                                  short* __restrict__ o, int total) {
  int idx = blockIdx.x * 256 + threadIdx.x;
  if (idx < total) o[idx] = f2bf(w[idx]);
}

// ---------- conv1 MFMA: x [S,3,8,8] f32 -> c1 [S,4,4,32] bf16 (pooled) ----------
// Block: 8 samples. LDS-staged padded [8][10][10][4] bf16 frame; wave w does
// samples w*2, w*2+1.
__global__ __launch_bounds__(256) void conv1_mfma(
    const float* __restrict__ x, const short* __restrict__ B1,
    const float* __restrict__ bias, const float* __restrict__ g,
    const float* __restrict__ be, short* __restrict__ c1) {
  __shared__ short sx[8 * 400];  // 8 samples x 10x10 cells x 4ic, 6.4 KB
  const int tid = threadIdx.x;
  const int s0 = blockIdx.x * 8;
  // zero padded frame (3200 shorts = 400 x uint4)
  for (int i = tid; i < 400; i += 256)
    *(uint4*)(sx + i * 8) = (uint4){0, 0, 0, 0};
  __syncthreads();
  // fill interior: 512 pixel-tasks, coalesced fp32 reads
  for (int p = tid; p < 512; p += 256) {
    const int si = p >> 6, pix = p & 63;
    const int y = pix >> 3, xx2 = pix & 7;
    const float* xb = x + (s0 + si) * 192 + pix;
    ushort4 o;
    o.x = (unsigned short)f2bf(xb[0]);
    o.y = (unsigned short)f2bf(xb[64]);
    o.z = (unsigned short)f2bf(xb[128]);
    o.w = 0;
    *(ushort4*)(sx + si * 400 + ((y + 1) * 10 + xx2 + 1) * 4) = o;
  }
  __syncthreads();
  const int lane = tid & 63, w = tid >> 6;
  const int col = lane & 15, quad = lane >> 4;
  bf16x8 Bf[2][2];
#pragma unroll
  for (int nt = 0; nt < 2; ++nt)
#pragma unroll
    for (int ks = 0; ks < 2; ++ks)
      Bf[nt][ks] = *(const bf16x8*)(B1 + (nt * 16 + col) * 64 + ks * 32 + quad * 8);
  float Abn[2], Cbn[2];
#pragma unroll
  for (int nt = 0; nt < 2; ++nt) {
    int oc = nt * 16 + col;
    float a = g[oc] * rsqrtf(1.0f + 1e-5f);
    Abn[nt] = a;
    Cbn[nt] = fmaf(bias[oc], a, be[oc]);
  }
  const int t0 = 2 * quad, t1 = t0 + 1;
  const int ky0 = t0 / 3, kx0 = t0 - 3 * (t0 / 3);
  const int ky1 = t1 / 3, kx1 = t1 - 3 * (t1 / 3);
  const int m = lane & 15;
  const int pl = m >> 2, sub = m & 3;
  const int dy = sub >> 1, dx = sub & 1;
  const uint2 z2 = {0u, 0u};
#pragma unroll
  for (int sl = 0; sl < 2; ++sl) {
    const int si = w * 2 + sl;
    const int s = s0 + si;
    const short* xb = sx + si * 400;
#pragma unroll
    for (int tile = 0; tile < 4; ++tile) {
      const int pi = tile * 4 + pl;
      const int py = pi >> 2, px = pi & 3;
      const int cy = 2 * py + dy, cx = 2 * px + dx;
      union { bf16x8 v; uint2 u[2]; } a0, a1;
      a0.u[0] = *(const uint2*)(xb + ((cy + ky0) * 10 + cx + kx0) * 4);
      a0.u[1] = *(const uint2*)(xb + ((cy + ky1) * 10 + cx + kx1) * 4);
      uint2 u8 = *(const uint2*)(xb + ((cy + 2) * 10 + cx + 2) * 4);
      a1.u[0] = (quad == 0) ? u8 : z2;
      a1.u[1] = z2;
      f32x4 acc0 = {0, 0, 0, 0}, acc1 = {0, 0, 0, 0};
      acc0 = __builtin_amdgcn_mfma_f32_16x16x32_bf16(a0.v, Bf[0][0], acc0, 0, 0, 0);
      acc0 = __builtin_amdgcn_mfma_f32_16x16x32_bf16(a1.v, Bf[0][1], acc0, 0, 0, 0);
      acc1 = __builtin_amdgcn_mfma_f32_16x16x32_bf16(a0.v, Bf[1][0], acc1, 0, 0, 0);
      acc1 = __builtin_amdgcn_mfma_f32_16x16x32_bf16(a1.v, Bf[1][1], acc1, 0, 0, 0);
      const int piq = tile * 4 + quad;
#pragma unroll
      for (int nt = 0; nt < 2; ++nt) {
        f32x4 acc = nt ? acc1 : acc0;
        float p0 = fmaf(acc[0], Abn[nt], Cbn[nt]);
        float p1 = fmaf(acc[1], Abn[nt], Cbn[nt]);
        float p2 = fmaf(acc[2], Abn[nt], Cbn[nt]);
        float p3 = fmaf(acc[3], Abn[nt], Cbn[nt]);
        float mx = fmaxf(fmaxf(fmaxf(p0, p1), fmaxf(p2, p3)), 0.0f);
        c1[s * 512 + piq * 32 + nt * 16 + col] = f2bf(mx);
      }
    }
  }
}

// ---------- conv2 MFMA: c1 [S,4,4,32] -> c2 [S,2,2,64] bf16 ----------
__global__ __launch_bounds__(256, 2) void conv2_mfma(
    const short* __restrict__ c1, const short* __restrict__ B2,
    const float* __restrict__ bias, const float* __restrict__ g,
    const float* __restrict__ be, short* __restrict__ c2) {
  const int lane = threadIdx.x & 63;
  const int wid = blockIdx.x * 4 + (threadIdx.x >> 6);
  const int col = lane & 15, quad = lane >> 4;
  bf16x8 Bf[4][9];
#pragma unroll
  for (int nt = 0; nt < 4; ++nt)
#pragma unroll
    for (int t = 0; t < 9; ++t)
      Bf[nt][t] = *(const bf16x8*)(B2 + (nt * 16 + col) * 288 + t * 32 + quad * 8);
  float Abn[4], Cbn[4];
#pragma unroll
  for (int nt = 0; nt < 4; ++nt) {
    int oc = nt * 16 + col;
    float a = g[oc] * rsqrtf(1.0f + 1e-5f);
    Abn[nt] = a;
    Cbn[nt] = fmaf(bias[oc], a, be[oc]);
  }
  const int m = lane & 15;
  const int q2 = m >> 2, sub = m & 3;
  const int cy = 2 * (q2 >> 1) + (sub >> 1);
  const int cx = 2 * (q2 & 1) + (sub & 1);
  int off[9];
  bool valid[9];
#pragma unroll
  for (int t = 0; t < 9; ++t) {
    int ky = t / 3, kx = t - 3 * (t / 3);
    int yy = cy + ky - 1, xx = cx + kx - 1;
    valid[t] = ((unsigned)yy < 4u) && ((unsigned)xx < 4u);
    int yc = min(max(yy, 0), 3), xc = min(max(xx, 0), 3);
    off[t] = (yc * 4 + xc) * 32 + quad * 8;
  }
  const bf16x8 zf = {0, 0, 0, 0, 0, 0, 0, 0};
#pragma unroll 1
  for (int si = 0; si < 8; ++si) {
    const int s = wid * 8 + si;
    const short* ib = c1 + s * 512;
    f32x4 acc[4];
#pragma unroll
    for (int nt = 0; nt < 4; ++nt) acc[nt] = (f32x4){0, 0, 0, 0};
#pragma unroll
    for (int t = 0; t < 9; ++t) {
      bf16x8 a = *(const bf16x8*)(ib + off[t]);
      if (!valid[t]) a = zf;
#pragma unroll
      for (int nt = 0; nt < 4; ++nt)
        acc[nt] = __builtin_amdgcn_mfma_f32_16x16x32_bf16(a, Bf[nt][t], acc[nt], 0, 0, 0);
    }
    short* ob = c2 + s * 256;
#pragma unroll
    for (int nt = 0; nt < 4; ++nt) {
      float p0 = fmaf(acc[nt][0], Abn[nt], Cbn[nt]);
      float p1 = fmaf(acc[nt][1], Abn[nt], Cbn[nt]);
      float p2 = fmaf(acc[nt][2], Abn[nt], Cbn[nt]);
      float p3 = fmaf(acc[nt][3], Abn[nt], Cbn[nt]);
      float mx = fmaxf(fmaxf(fmaxf(p0, p1), fmaxf(p2, p3)), 0.0f);
      ob[quad * 64 + nt * 16 + col] = f2bf(mx);  // pooled cell == quad
    }
  }
}

// ---------- conv3 MFMA: c2 [S,2,2,64] -> c3 [S,128] bf16; A fetched ONCE ----------
__global__ __launch_bounds__(256) void conv3_mfma(
    const short* __restrict__ c2, const short* __restrict__ B3,
    const float* __restrict__ bias, const float* __restrict__ g,
    const float* __restrict__ be, short* __restrict__ c3) {
  __shared__ short sB[32 * 584];  // 32 oc rows x K=576, +8 pad
  const int tid = threadIdx.x;
  const int lane = tid & 63, w = tid >> 6;
  const int col = lane & 15, quad = lane >> 4;
  const int m = lane & 15;
  const int cp = m & 3, sl = m >> 2;
  const int cy = cp >> 1, cx = cp & 1;
  const int s = blockIdx.x * 16 + w * 4 + sl;
  const short* ib = c2 + s * 256;
  bf16x8 A[18];
  const bf16x8 zf = {0, 0, 0, 0, 0, 0, 0, 0};
#pragma unroll
  for (int ks = 0; ks < 18; ++ks) {
    int t = ks >> 1;
    int ky = t / 3, kx = t - 3 * (t / 3);
    int iy = cy + ky - 1, ix = cx + kx - 1;
    bool valid = ((unsigned)iy < 2u) && ((unsigned)ix < 2u);
    int iyc = min(max(iy, 0), 1), ixc = min(max(ix, 0), 1);
    bf16x8 a = *(const bf16x8*)(ib + (iyc * 2 + ixc) * 64 + (ks & 1) * 32 + quad * 8);
    A[ks] = valid ? a : zf;
  }
  f32x4 acc[8];
#pragma unroll
  for (int i = 0; i < 8; ++i) acc[i] = (f32x4){0, 0, 0, 0};
#pragma unroll
  for (int ng = 0; ng < 4; ++ng) {
    __syncthreads();
#pragma unroll
    for (int it = 0; it < 9; ++it) {
      int cidx = it * 256 + tid;
      int row = cidx / 72, seg = cidx - row * 72;
      *(bf16x8*)(sB + row * 584 + seg * 8) =
          *(const bf16x8*)(B3 + (ng * 32 + row) * 576 + seg * 8);
    }
    __syncthreads();
#pragma unroll
    for (int nt = 0; nt < 2; ++nt) {
      const int nB = (nt * 16 + col) * 584 + quad * 8;
#pragma unroll
      for (int ks = 0; ks < 18; ++ks) {
        bf16x8 b = *(const bf16x8*)(sB + nB + ks * 32);
        acc[ng * 2 + nt] =
            __builtin_amdgcn_mfma_f32_16x16x32_bf16(A[ks], b, acc[ng * 2 + nt], 0, 0, 0);
      }
    }
  }
  const int sample = blockIdx.x * 16 + w * 4 + quad;
#pragma unroll
  for (int i = 0; i < 8; ++i) {
    int oc = (i >> 1) * 32 + (i & 1) * 16 + col;
    float a = g[oc] * rsqrtf(1.0f + 1e-5f);
    float cc = fmaf(bias[oc], a, be[oc]);
    float p0 = fmaf(acc[i][0], a, cc);
    float p1 = fmaf(acc[i][1], a, cc);
    float p2 = fmaf(acc[i][2], a, cc);
    float p3 = fmaf(acc[i][3], a, cc);
    float mx = fmaxf(fmaxf(fmaxf(p0, p1), fmaxf(p2, p3)), 0.0f);
    c3[sample * 128 + oc] = f2bf(mx);
  }
}

// ---------- ahat: gso[b] + I, sym-normalized (fp32) ----------
__global__ __launch_bounds__(256) void ahat_kernel(
    const float* __restrict__ gso, float* __restrict__ ahat) {
  __shared__ float s_a[4096];
  __shared__ float s_d[64];
  const int bb = blockIdx.x;
  const int tid = threadIdx.x;
  for (int i = tid; i < 4096; i += 256) {
    const int r = i >> 6, c = i & 63;
    s_a[i] = gso[bb * 4096 + i] + (r == c ? 1.0f : 0.0f);
  }
  __syncthreads();
  if (tid < 64) {
    float sum = 0.0f;
    for (int j = 0; j < 64; ++j) sum += s_a[j * 64 + tid];
    s_d[tid] = rsqrtf(sum);
  }
  __syncthreads();
  for (int i = tid; i < 4096; i += 256) {
    const int r = i >> 6, c = i & 63;
    ahat[bb * 4096 + i] = s_d[r] * s_a[i] * s_d[c];
  }
}

// ---------- bf16 GEMM: X[M,128] @ Wb[128,128](row=n) -> out bf16 ----------
__global__ __launch_bounds__(256) void gemm_bf16(
    const short* __restrict__ X, const short* __restrict__ Wb,
    const float* __restrict__ bias, short* __restrict__ out, int relu) {
  __shared__ short sW[128 * 136];
  const int tid = threadIdx.x;
#pragma unroll
  for (int it = 0; it < 8; ++it) {
    int cidx = it * 256 + tid;
    int row = cidx >> 4, seg = cidx & 15;
    *(bf16x8*)(sW + row * 136 + seg * 8) = *(const bf16x8*)(Wb + row * 128 + seg * 8);
  }
  __syncthreads();
  const int lane = tid & 63, w = tid >> 6;
  const int col = lane & 15, quad = lane >> 4;
  const int sA = blockIdx.x * 64 + w * 16 + col;
  bf16x8 A[4];
#pragma unroll
  for (int ks = 0; ks < 4; ++ks)
    A[ks] = *(const bf16x8*)(X + sA * 128 + ks * 32 + quad * 8);
  f32x4 acc[8];
#pragma unroll
  for (int i = 0; i < 8; ++i) acc[i] = (f32x4){0, 0, 0, 0};
#pragma unroll
  for (int nt = 0; nt < 8; ++nt) {
    const int nB = (nt * 16 + col) * 136 + quad * 8;
#pragma unroll
    for (int ks = 0; ks < 4; ++ks) {
      bf16x8 b = *(const bf16x8*)(sW + nB + ks * 32);
      acc[nt] = __builtin_amdgcn_mfma_f32_16x16x32_bf16(A[ks], b, acc[nt], 0, 0, 0);
    }
  }
  const int so = blockIdx.x * 64 + w * 16 + quad * 4;
#pragma unroll
  for (int nt = 0; nt < 8; ++nt) {
    const int n = nt * 16 + col;
    const float bv = bias ? bias[n] : 0.0f;
#pragma unroll
    for (int reg = 0; reg < 4; ++reg) {
      float v = acc[nt][reg] + bv;
      if (relu) v = fmaxf(v, 0.0f);
      out[(so + reg) * 128 + n] = f2bf(v);
    }
  }
}

// ---------- agg: out[b] = relu(ahat[b] @ T[b] + bias); fp32 math, bf16 I/O ----------
__global__ __launch_bounds__(256) void agg_kernel(
    const float* __restrict__ ahat, const short* __restrict__ T,
    const float* __restrict__ bias, short* __restrict__ out) {
  __shared__ float s_a[4096];
  __shared__ float s_t[4096];
  const int bb = blockIdx.x;
  const int half = blockIdx.y;
  const int tid = threadIdx.x;
  const int c = tid & 63;
  const int f = (half << 6) + c;
  const int ib = tid >> 6;
  for (int i = tid; i < 4096; i += 256) s_a[i] = ahat[bb * 4096 + i];
  for (int i = tid; i < 4096; i += 256) {
    const int j = i >> 6, cc = i & 63;
    s_t[i] = bf2f((unsigned short)T[bb * 8192 + j * 128 + (half << 6) + cc]);
  }
  __syncthreads();
  float acc[16];
  for (int r = 0; r < 16; ++r) acc[r] = 0.0f;
  for (int j = 0; j < 64; ++j) {
    const float tv = s_t[j * 64 + c];
    for (int r = 0; r < 16; ++r)
      acc[r] = fmaf(s_a[(ib + 4 * r) * 64 + j], tv, acc[r]);
  }
  const float bv = bias[f];
  for (int r = 0; r < 16; ++r) {
    const int i = ib + 4 * r;
    out[bb * 8192 + i * 128 + f] = f2bf(fmaxf(acc[r] + bv, 0.0f));
  }
}

// ---------- head: [S,128]bf16 @ w_out[5,128]^T + b -> fp32 ----------
__global__ __launch_bounds__(256) void head_kernel(
    const short* __restrict__ H, const float* __restrict__ Wo,
    const float* __restrict__ bo, float* __restrict__ out) {
  __shared__ float s_w[640];
  __shared__ float s_b[5];
  const int tid = threadIdx.x;
  for (int i = tid; i < 640; i += 256) s_w[i] = Wo[i];
  if (tid < 5) s_b[tid] = bo[tid];
  __syncthreads();
  const int s = blockIdx.x * 256 + tid;
  float acc[5] = {0.f, 0.f, 0.f, 0.f, 0.f};
#pragma unroll
  for (int k8 = 0; k8 < 16; ++k8) {
    union { bf16x8 v; unsigned short u[8]; } h;
    h.v = *(const bf16x8*)(H + s * 128 + k8 * 8);
#pragma unroll
    for (int j = 0; j < 8; ++j) {
      float hv = bf2f(h.u[j]);
      for (int o = 0; o < 5; ++o)
        acc[o] = fmaf(hv, s_w[o * 128 + k8 * 8 + j], acc[o]);
    }
  }
  for (int o = 0; o < 5; ++o) out[s * 5 + o] = acc[o] + s_b[o];
}

extern "C" void kernel_launch(void* const* d_in, const int* in_sizes, int n_in,
                              void* d_out, int out_size, void* d_ws, size_t ws_size,
                              hipStream_t stream) {
  const float* x    = (const float*)d_in[0];
  const float* gso  = (const float*)d_in[1];
  const float* w_c1 = (const float*)d_in[2];
  const float* b_c1 = (const float*)d_in[3];
  const float* g_b1 = (const float*)d_in[4];
  const float* e_b1 = (const float*)d_in[5];
  const float* w_c2 = (const float*)d_in[6];
  const float* b_c2 = (const float*)d_in[7];
  const float* g_b2 = (const float*)d_in[8];
  const float* e_b2 = (const float*)d_in[9];
  const float* w_c3 = (const float*)d_in[10];
  const float* b_c3 = (const float*)d_in[11];
  const float* g_b3 = (const float*)d_in[12];
  const float* e_b3 = (const float*)d_in[13];
  const float* w_fc = (const float*)d_in[14];
  const float* b_fc = (const float*)d_in[15];
  const float* w_g1 = (const float*)d_in[16];
  const float* b_g1 = (const float*)d_in[17];
  const float* w_g2 = (const float*)d_in[18];
  const float* b_g2 = (const float*)d_in[19];
  const float* w_o  = (const float*)d_in[20];
  const float* b_o  = (const float*)d_in[21];
  float* out = (float*)d_out;
  char* ws = (char*)d_ws;

  // workspace layout (bytes) — NO ALIASING, total 54,812,672 (< proven 58.72 MB)
  short* c1   = (short*)(ws + 0);          // 16,777,216
  short* c2   = (short*)(ws + 16777216);   //  8,388,608
  short* c3   = (short*)(ws + 25165824);   //  4,194,304
  short* feat = (short*)(ws + 29360128);   //  4,194,304
  short* tmp1 = (short*)(ws + 33554432);   //  4,194,304
  short* hg1  = (short*)(ws + 37748736);   //  4,194,304
  short* tmp2 = (short*)(ws + 41943040);   //  4,194,304
  short* hg2  = (short*)(ws + 46137344);   //  4,194,304
  float* ahat = (float*)(ws + 50331648);   //  4,194,304
  short* B1   = (short*)(ws + 54525952);   //  4,096
  short* B2   = (short*)(ws + 54530048);   //  36,864
  short* B3   = (short*)(ws + 54566912);   //  147,456
  short* Wfc  = (short*)(ws + 54714368);   //  32,768
  short* Wg1  = (short*)(ws + 54747136);   //  32,768
  short* Wg2  = (short*)(ws + 54779904);   //  32,768

  pack1<<<8, 256, 0, stream>>>(w_c1, B1);
  pack_tmaj<<<72, 256, 0, stream>>>(w_c2, B2, 32, 18432);
  pack_tmaj<<<288, 256, 0, stream>>>(w_c3, B3, 64, 73728);
  pack_dense<<<64, 256, 0, stream>>>(w_fc, Wfc, 16384);
  pack_dense<<<64, 256, 0, stream>>>(w_g1, Wg1, 16384);
  pack_dense<<<64, 256, 0, stream>>>(w_g2, Wg2, 16384);
  conv1_mfma<<<2048, 256, 0, stream>>>(x, B1, b_c1, g_b1, e_b1, c1);
  conv2_mfma<<<512, 256, 0, stream>>>(c1, B2, b_c2, g_b2, e_b2, c2);
  conv3_mfma<<<1024, 256, 0, stream>>>(c2, B3, b_c3, g_b3, e_b3, c3);
  ahat_kernel<<<256, 256, 0, stream>>>(gso, ahat);
  gemm_bf16<<<256, 256, 0, stream>>>(c3, Wfc, b_fc, feat, 1);
  gemm_bf16<<<256, 256, 0, stream>>>(feat, Wg1, nullptr, tmp1, 0);
  agg_kernel<<<dim3(256, 2), 256, 0, stream>>>(ahat, tmp1, b_g1, hg1);
  gemm_bf16<<<256, 256, 0, stream>>>(hg1, Wg2, nullptr, tmp2, 0);
  agg_kernel<<<dim3(256, 2), 256, 0, stream>>>(ahat, tmp2, b_g2, hg2);
  head_kernel<<<64, 256, 0, stream>>>(hg2, w_o, b_o, out);
}

// Round 7
// 176.670 us; speedup vs baseline: 2.9779x; 1.2420x over previous
//
#include <hip/hip_runtime.h>
#include <math.h>

// Net_19335942767008 round 7: round 6 with the fused_dense c3-staging index
// bug fixed (r=i>>4, seg=i&15 — was >>3/&7, overflowing sAct into sT/sAhat).
// Convs byte-identical to validated round 5. No workspace aliasing.

typedef __attribute__((ext_vector_type(8))) short bf16x8;
typedef __attribute__((ext_vector_type(4))) float f32x4;

__device__ __forceinline__ short f2bf(float f) {
  union { float f; unsigned u; } v; v.f = f;
  unsigned r = v.u + 0x7fffu + ((v.u >> 16) & 1u);
  return (short)(r >> 16);
}
__device__ __forceinline__ float bf2f(unsigned short u) {
  union { unsigned u; float f; } v; v.u = ((unsigned)u) << 16;
  return v.f;
}

// ---------- all weight packs in one kernel ----------
__global__ __launch_bounds__(256) void pack_all(
    const float* __restrict__ w_c1, const float* __restrict__ w_c2,
    const float* __restrict__ w_c3, const float* __restrict__ w_fc,
    const float* __restrict__ w_g1, const float* __restrict__ w_g2,
    short* __restrict__ B1, short* __restrict__ B2, short* __restrict__ B3,
    short* __restrict__ Wfc, short* __restrict__ Wg1, short* __restrict__ Wg2) {
  int idx = blockIdx.x * 256 + threadIdx.x;
  if (idx < 2048) {  // B1: [oc][t][ic4], taps 0..8 + zero pad
    int oc = idx >> 6, k = idx & 63;
    int t = k >> 2, ic = k & 3;
    float v = (t < 9 && ic < 3) ? w_c1[(oc * 3 + ic) * 9 + t] : 0.0f;
    B1[idx] = f2bf(v);
  } else if (idx < 20480) {  // B2: [oc][t][ic], IC=32
    int i2 = idx - 2048;
    int oc = i2 / 288, r = i2 - oc * 288;
    int t = r >> 5, ic = r & 31;
    B2[i2] = f2bf(w_c2[(oc * 32 + ic) * 9 + t]);
  } else if (idx < 94208) {  // B3: [oc][t][ic], IC=64
    int i3 = idx - 20480;
    int oc = i3 / 576, r = i3 - oc * 576;
    int t = r >> 6, ic = r & 63;
    B3[i3] = f2bf(w_c3[(oc * 64 + ic) * 9 + t]);
  } else if (idx < 110592) {
    int i = idx - 94208; Wfc[i] = f2bf(w_fc[i]);
  } else if (idx < 126976) {
    int i = idx - 110592; Wg1[i] = f2bf(w_g1[i]);
  } else if (idx < 143360) {
    int i = idx - 126976; Wg2[i] = f2bf(w_g2[i]);
  }
}

// ---------- conv1 MFMA: x [S,3,8,8] f32 -> c1 [S,4,4,32] bf16 (pooled) ----------
__global__ __launch_bounds__(256) void conv1_mfma(
    const float* __restrict__ x, const short* __restrict__ B1,
    const float* __restrict__ bias, const float* __restrict__ g,
    const float* __restrict__ be, short* __restrict__ c1) {
  __shared__ short sx[8 * 400];
  const int tid = threadIdx.x;
  const int s0 = blockIdx.x * 8;
  for (int i = tid; i < 400; i += 256)
    *(uint4*)(sx + i * 8) = (uint4){0, 0, 0, 0};
  __syncthreads();
  for (int p = tid; p < 512; p += 256) {
    const int si = p >> 6, pix = p & 63;
    const int y = pix >> 3, xx2 = pix & 7;
    const float* xb = x + (s0 + si) * 192 + pix;
    ushort4 o;
    o.x = (unsigned short)f2bf(xb[0]);
    o.y = (unsigned short)f2bf(xb[64]);
    o.z = (unsigned short)f2bf(xb[128]);
    o.w = 0;
    *(ushort4*)(sx + si * 400 + ((y + 1) * 10 + xx2 + 1) * 4) = o;
  }
  __syncthreads();
  const int lane = tid & 63, w = tid >> 6;
  const int col = lane & 15, quad = lane >> 4;
  bf16x8 Bf[2][2];
#pragma unroll
  for (int nt = 0; nt < 2; ++nt)
#pragma unroll
    for (int ks = 0; ks < 2; ++ks)
      Bf[nt][ks] = *(const bf16x8*)(B1 + (nt * 16 + col) * 64 + ks * 32 + quad * 8);
  float Abn[2], Cbn[2];
#pragma unroll
  for (int nt = 0; nt < 2; ++nt) {
    int oc = nt * 16 + col;
    float a = g[oc] * rsqrtf(1.0f + 1e-5f);
    Abn[nt] = a;
    Cbn[nt] = fmaf(bias[oc], a, be[oc]);
  }
  const int t0 = 2 * quad, t1 = t0 + 1;
  const int ky0 = t0 / 3, kx0 = t0 - 3 * (t0 / 3);
  const int ky1 = t1 / 3, kx1 = t1 - 3 * (t1 / 3);
  const int m = lane & 15;
  const int pl = m >> 2, sub = m & 3;
  const int dy = sub >> 1, dx = sub & 1;
  const uint2 z2 = {0u, 0u};
#pragma unroll
  for (int sl = 0; sl < 2; ++sl) {
    const int si = w * 2 + sl;
    const int s = s0 + si;
    const short* xb = sx + si * 400;
#pragma unroll
    for (int tile = 0; tile < 4; ++tile) {
      const int pi = tile * 4 + pl;
      const int py = pi >> 2, px = pi & 3;
      const int cy = 2 * py + dy, cx = 2 * px + dx;
      union { bf16x8 v; uint2 u[2]; } a0, a1;
      a0.u[0] = *(const uint2*)(xb + ((cy + ky0) * 10 + cx + kx0) * 4);
      a0.u[1] = *(const uint2*)(xb + ((cy + ky1) * 10 + cx + kx1) * 4);
      uint2 u8 = *(const uint2*)(xb + ((cy + 2) * 10 + cx + 2) * 4);
      a1.u[0] = (quad == 0) ? u8 : z2;
      a1.u[1] = z2;
      f32x4 acc0 = {0, 0, 0, 0}, acc1 = {0, 0, 0, 0};
      acc0 = __builtin_amdgcn_mfma_f32_16x16x32_bf16(a0.v, Bf[0][0], acc0, 0, 0, 0);
      acc0 = __builtin_amdgcn_mfma_f32_16x16x32_bf16(a1.v, Bf[0][1], acc0, 0, 0, 0);
      acc1 = __builtin_amdgcn_mfma_f32_16x16x32_bf16(a0.v, Bf[1][0], acc1, 0, 0, 0);
      acc1 = __builtin_amdgcn_mfma_f32_16x16x32_bf16(a1.v, Bf[1][1], acc1, 0, 0, 0);
      const int piq = tile * 4 + quad;
#pragma unroll
      for (int nt = 0; nt < 2; ++nt) {
        f32x4 acc = nt ? acc1 : acc0;
        float p0 = fmaf(acc[0], Abn[nt], Cbn[nt]);
        float p1 = fmaf(acc[1], Abn[nt], Cbn[nt]);
        float p2 = fmaf(acc[2], Abn[nt], Cbn[nt]);
        float p3 = fmaf(acc[3], Abn[nt], Cbn[nt]);
        float mx = fmaxf(fmaxf(fmaxf(p0, p1), fmaxf(p2, p3)), 0.0f);
        c1[s * 512 + piq * 32 + nt * 16 + col] = f2bf(mx);
      }
    }
  }
}

// ---------- conv2 MFMA: c1 [S,4,4,32] -> c2 [S,2,2,64] bf16 ----------
__global__ __launch_bounds__(256, 2) void conv2_mfma(
    const short* __restrict__ c1, const short* __restrict__ B2,
    const float* __restrict__ bias, const float* __restrict__ g,
    const float* __restrict__ be, short* __restrict__ c2) {
  const int lane = threadIdx.x & 63;
  const int wid = blockIdx.x * 4 + (threadIdx.x >> 6);
  const int col = lane & 15, quad = lane >> 4;
  bf16x8 Bf[4][9];
#pragma unroll
  for (int nt = 0; nt < 4; ++nt)
#pragma unroll
    for (int t = 0; t < 9; ++t)
      Bf[nt][t] = *(const bf16x8*)(B2 + (nt * 16 + col) * 288 + t * 32 + quad * 8);
  float Abn[4], Cbn[4];
#pragma unroll
  for (int nt = 0; nt < 4; ++nt) {
    int oc = nt * 16 + col;
    float a = g[oc] * rsqrtf(1.0f + 1e-5f);
    Abn[nt] = a;
    Cbn[nt] = fmaf(bias[oc], a, be[oc]);
  }
  const int m = lane & 15;
  const int q2 = m >> 2, sub = m & 3;
  const int cy = 2 * (q2 >> 1) + (sub >> 1);
  const int cx = 2 * (q2 & 1) + (sub & 1);
  int off[9];
  bool valid[9];
#pragma unroll
  for (int t = 0; t < 9; ++t) {
    int ky = t / 3, kx = t - 3 * (t / 3);
    int yy = cy + ky - 1, xx = cx + kx - 1;
    valid[t] = ((unsigned)yy < 4u) && ((unsigned)xx < 4u);
    int yc = min(max(yy, 0), 3), xc = min(max(xx, 0), 3);
    off[t] = (yc * 4 + xc) * 32 + quad * 8;
  }
  const bf16x8 zf = {0, 0, 0, 0, 0, 0, 0, 0};
#pragma unroll 1
  for (int si = 0; si < 8; ++si) {
    const int s = wid * 8 + si;
    const short* ib = c1 + s * 512;
    f32x4 acc[4];
#pragma unroll
    for (int nt = 0; nt < 4; ++nt) acc[nt] = (f32x4){0, 0, 0, 0};
#pragma unroll
    for (int t = 0; t < 9; ++t) {
      bf16x8 a = *(const bf16x8*)(ib + off[t]);
      if (!valid[t]) a = zf;
#pragma unroll
      for (int nt = 0; nt < 4; ++nt)
        acc[nt] = __builtin_amdgcn_mfma_f32_16x16x32_bf16(a, Bf[nt][t], acc[nt], 0, 0, 0);
    }
    short* ob = c2 + s * 256;
#pragma unroll
    for (int nt = 0; nt < 4; ++nt) {
      float p0 = fmaf(acc[nt][0], Abn[nt], Cbn[nt]);
      float p1 = fmaf(acc[nt][1], Abn[nt], Cbn[nt]);
      float p2 = fmaf(acc[nt][2], Abn[nt], Cbn[nt]);
      float p3 = fmaf(acc[nt][3], Abn[nt], Cbn[nt]);
      float mx = fmaxf(fmaxf(fmaxf(p0, p1), fmaxf(p2, p3)), 0.0f);
      ob[quad * 64 + nt * 16 + col] = f2bf(mx);
    }
  }
}

// ---------- conv3 MFMA: c2 [S,2,2,64] -> c3 [S,128] bf16 ----------
__global__ __launch_bounds__(256) void conv3_mfma(
    const short* __restrict__ c2, const short* __restrict__ B3,
    const float* __restrict__ bias, const float* __restrict__ g,
    const float* __restrict__ be, short* __restrict__ c3) {
  __shared__ short sB[32 * 584];
  const int tid = threadIdx.x;
  const int lane = tid & 63, w = tid >> 6;
  const int col = lane & 15, quad = lane >> 4;
  const int m = lane & 15;
  const int cp = m & 3, sl = m >> 2;
  const int cy = cp >> 1, cx = cp & 1;
  const int s = blockIdx.x * 16 + w * 4 + sl;
  const short* ib = c2 + s * 256;
  bf16x8 A[18];
  const bf16x8 zf = {0, 0, 0, 0, 0, 0, 0, 0};
#pragma unroll
  for (int ks = 0; ks < 18; ++ks) {
    int t = ks >> 1;
    int ky = t / 3, kx = t - 3 * (t / 3);
    int iy = cy + ky - 1, ix = cx + kx - 1;
    bool valid = ((unsigned)iy < 2u) && ((unsigned)ix < 2u);
    int iyc = min(max(iy, 0), 1), ixc = min(max(ix, 0), 1);
    bf16x8 a = *(const bf16x8*)(ib + (iyc * 2 + ixc) * 64 + (ks & 1) * 32 + quad * 8);
    A[ks] = valid ? a : zf;
  }
  f32x4 acc[8];
#pragma unroll
  for (int i = 0; i < 8; ++i) acc[i] = (f32x4){0, 0, 0, 0};
#pragma unroll
  for (int ng = 0; ng < 4; ++ng) {
    __syncthreads();
#pragma unroll
    for (int it = 0; it < 9; ++it) {
      int cidx = it * 256 + tid;
      int row = cidx / 72, seg = cidx - row * 72;
      *(bf16x8*)(sB + row * 584 + seg * 8) =
          *(const bf16x8*)(B3 + (ng * 32 + row) * 576 + seg * 8);
    }
    __syncthreads();
#pragma unroll
    for (int nt = 0; nt < 2; ++nt) {
      const int nB = (nt * 16 + col) * 584 + quad * 8;
#pragma unroll
      for (int ks = 0; ks < 18; ++ks) {
        bf16x8 b = *(const bf16x8*)(sB + nB + ks * 32);
        acc[ng * 2 + nt] =
            __builtin_amdgcn_mfma_f32_16x16x32_bf16(A[ks], b, acc[ng * 2 + nt], 0, 0, 0);
      }
    }
  }
  const int sample = blockIdx.x * 16 + w * 4 + quad;
#pragma unroll
  for (int i = 0; i < 8; ++i) {
    int oc = (i >> 1) * 32 + (i & 1) * 16 + col;
    float a = g[oc] * rsqrtf(1.0f + 1e-5f);
    float cc = fmaf(bias[oc], a, be[oc]);
    float p0 = fmaf(acc[i][0], a, cc);
    float p1 = fmaf(acc[i][1], a, cc);
    float p2 = fmaf(acc[i][2], a, cc);
    float p3 = fmaf(acc[i][3], a, cc);
    float mx = fmaxf(fmaxf(fmaxf(p0, p1), fmaxf(p2, p3)), 0.0f);
    c3[sample * 128 + oc] = f2bf(mx);
  }
}

// ---------- fused dense tail: one block per batch ----------
__global__ __launch_bounds__(256) void fused_dense(
    const short* __restrict__ c3, const float* __restrict__ gso,
    const short* __restrict__ Wfc, const short* __restrict__ Wg1,
    const short* __restrict__ Wg2, const float* __restrict__ b_fc,
    const float* __restrict__ b_g1, const float* __restrict__ b_g2,
    const float* __restrict__ w_o, const float* __restrict__ b_o,
    float* __restrict__ out) {
  __shared__ short sAct[64 * 136];   // activation rows [agent][feat], +8 pad
  __shared__ short sT[128 * 72];     // P^T [n][agent], +8 pad; aliased gso f32 in S0-S2
  __shared__ short sAhat[64 * 72];   // ahat bf16 [r][c], +8 pad
  __shared__ float sDinv[64];
  __shared__ float sWo[640];
  const int tid = threadIdx.x;
  const int b = blockIdx.x;
  float* sG = (float*)sT;  // 4096 f32 = 16 KB <= 18.4 KB
  // S0: stage gso + Wo
  for (int i = tid; i < 4096; i += 256) sG[i] = gso[b * 4096 + i];
  for (int i = tid; i < 640; i += 256) sWo[i] = w_o[i];
  __syncthreads();
  // S1: dinv via column sums (gso symmetric, diag 0; +1 self loop)
  if (tid < 64) {
    float ssum = 1.0f;
    for (int j = 0; j < 64; ++j) ssum += sG[j * 64 + tid];
    sDinv[tid] = rsqrtf(ssum);
  }
  __syncthreads();
  // S2: ahat bf16; stage c3 rows into sAct (64 rows x 16 segs of 8)
  for (int i = tid; i < 4096; i += 256) {
    int r = i >> 6, c = i & 63;
    float v = sDinv[r] * (sG[i] + (r == c ? 1.0f : 0.0f)) * sDinv[c];
    sAhat[r * 72 + c] = f2bf(v);
  }
  for (int i = tid; i < 1024; i += 256) {
    int r = i >> 4, seg = i & 15;  // FIXED (was >>3/&7: overflowed sAct)
    *(bf16x8*)(sAct + r * 136 + seg * 8) =
        *(const bf16x8*)(c3 + (b * 64 + r) * 128 + seg * 8);
  }
  __syncthreads();
  const int lane = tid & 63, w = tid >> 6;
  const int col = lane & 15, quad = lane >> 4;
  const int arow = (w * 16 + col) * 136;
  const int crow0 = (w * 16 + quad * 4) * 136;
  bf16x8 A[4];
  f32x4 acc[8];

  // ---- FC: sAct(c3) @ Wfc^T + b_fc, relu -> sAct ----
#pragma unroll
  for (int ks = 0; ks < 4; ++ks)
    A[ks] = *(const bf16x8*)(sAct + arow + ks * 32 + quad * 8);
  __syncthreads();
#pragma unroll
  for (int i = 0; i < 8; ++i) acc[i] = (f32x4){0, 0, 0, 0};
#pragma unroll
  for (int nt = 0; nt < 8; ++nt) {
    const int n = nt * 16 + col;
#pragma unroll
    for (int ks = 0; ks < 4; ++ks) {
      bf16x8 bb = *(const bf16x8*)(Wfc + n * 128 + ks * 32 + quad * 8);
      acc[nt] = __builtin_amdgcn_mfma_f32_16x16x32_bf16(A[ks], bb, acc[nt], 0, 0, 0);
    }
  }
#pragma unroll
  for (int nt = 0; nt < 8; ++nt) {
    const int n = nt * 16 + col;
    const float bv = b_fc[n];
#pragma unroll
    for (int reg = 0; reg < 4; ++reg)
      sAct[crow0 + reg * 136 + n] = f2bf(fmaxf(acc[nt][reg] + bv, 0.0f));
  }
  __syncthreads();

  // ---- G1: sAct(feat) @ Wg1^T -> sT transposed ----
#pragma unroll
  for (int ks = 0; ks < 4; ++ks)
    A[ks] = *(const bf16x8*)(sAct + arow + ks * 32 + quad * 8);
#pragma unroll
  for (int i = 0; i < 8; ++i) acc[i] = (f32x4){0, 0, 0, 0};
#pragma unroll
  for (int nt = 0; nt < 8; ++nt) {
    const int n = nt * 16 + col;
#pragma unroll
    for (int ks = 0; ks < 4; ++ks) {
      bf16x8 bb = *(const bf16x8*)(Wg1 + n * 128 + ks * 32 + quad * 8);
      acc[nt] = __builtin_amdgcn_mfma_f32_16x16x32_bf16(A[ks], bb, acc[nt], 0, 0, 0);
    }
  }
#pragma unroll
  for (int nt = 0; nt < 8; ++nt) {
    const int n = nt * 16 + col;
    ushort4 pk;
    pk.x = (unsigned short)f2bf(acc[nt][0]);
    pk.y = (unsigned short)f2bf(acc[nt][1]);
    pk.z = (unsigned short)f2bf(acc[nt][2]);
    pk.w = (unsigned short)f2bf(acc[nt][3]);
    *(ushort4*)(sT + n * 72 + w * 16 + quad * 4) = pk;
  }
  __syncthreads();

  // ---- AGG1: relu(ahat @ P + b_g1) -> sAct ----
  bf16x8 Ah[2];
#pragma unroll
  for (int ks = 0; ks < 2; ++ks)
    Ah[ks] = *(const bf16x8*)(sAhat + (w * 16 + col) * 72 + ks * 32 + quad * 8);
#pragma unroll
  for (int i = 0; i < 8; ++i) acc[i] = (f32x4){0, 0, 0, 0};
#pragma unroll
  for (int nt = 0; nt < 8; ++nt) {
    const int n = nt * 16 + col;
#pragma unroll
    for (int ks = 0; ks < 2; ++ks) {
      bf16x8 bb = *(const bf16x8*)(sT + n * 72 + ks * 32 + quad * 8);
      acc[nt] = __builtin_amdgcn_mfma_f32_16x16x32_bf16(Ah[ks], bb, acc[nt], 0, 0, 0);
    }
  }
#pragma unroll
  for (int nt = 0; nt < 8; ++nt) {
    const int n = nt * 16 + col;
    const float bv = b_g1[n];
#pragma unroll
    for (int reg = 0; reg < 4; ++reg)
      sAct[crow0 + reg * 136 + n] = f2bf(fmaxf(acc[nt][reg] + bv, 0.0f));
  }
  __syncthreads();

  // ---- G2: sAct(hg1) @ Wg2^T -> sT transposed ----
#pragma unroll
  for (int ks = 0; ks < 4; ++ks)
    A[ks] = *(const bf16x8*)(sAct + arow + ks * 32 + quad * 8);
#pragma unroll
  for (int i = 0; i < 8; ++i) acc[i] = (f32x4){0, 0, 0, 0};
#pragma unroll
  for (int nt = 0; nt < 8; ++nt) {
    const int n = nt * 16 + col;
#pragma unroll
    for (int ks = 0; ks < 4; ++ks) {
      bf16x8 bb = *(const bf16x8*)(Wg2 + n * 128 + ks * 32 + quad * 8);
      acc[nt] = __builtin_amdgcn_mfma_f32_16x16x32_bf16(A[ks], bb, acc[nt], 0, 0, 0);
    }
  }
#pragma unroll
  for (int nt = 0; nt < 8; ++nt) {
    const int n = nt * 16 + col;
    ushort4 pk;
    pk.x = (unsigned short)f2bf(acc[nt][0]);
    pk.y = (unsigned short)f2bf(acc[nt][1]);
    pk.z = (unsigned short)f2bf(acc[nt][2]);
    pk.w = (unsigned short)f2bf(acc[nt][3]);
    *(ushort4*)(sT + n * 72 + w * 16 + quad * 4) = pk;
  }
  __syncthreads();

  // ---- AGG2: relu(ahat @ P2 + b_g2) -> sAct ----
#pragma unroll
  for (int i = 0; i < 8; ++i) acc[i] = (f32x4){0, 0, 0, 0};
#pragma unroll
  for (int nt = 0; nt < 8; ++nt) {
    const int n = nt * 16 + col;
#pragma unroll
    for (int ks = 0; ks < 2; ++ks) {
      bf16x8 bb = *(const bf16x8*)(sT + n * 72 + ks * 32 + quad * 8);
      acc[nt] = __builtin_amdgcn_mfma_f32_16x16x32_bf16(Ah[ks], bb, acc[nt], 0, 0, 0);
    }
  }
#pragma unroll
  for (int nt = 0; nt < 8; ++nt) {
    const int n = nt * 16 + col;
    const float bv = b_g2[n];
#pragma unroll
    for (int reg = 0; reg < 4; ++reg)
      sAct[crow0 + reg * 136 + n] = f2bf(fmaxf(acc[nt][reg] + bv, 0.0f));
  }
  __syncthreads();

  // ---- HEAD: out[b,j,:] = hg2[j] @ Wo^T + b_o ----
  {
    const int j = tid >> 2, o = tid & 3;
    float a0 = 0.0f;
#pragma unroll
    for (int k8 = 0; k8 < 16; ++k8) {
      union { bf16x8 v; unsigned short u[8]; } h;
      h.v = *(const bf16x8*)(sAct + j * 136 + k8 * 8);
#pragma unroll
      for (int jj = 0; jj < 8; ++jj)
        a0 = fmaf(bf2f(h.u[jj]), sWo[o * 128 + k8 * 8 + jj], a0);
    }
    out[(b * 64 + j) * 5 + o] = a0 + b_o[o];
    if (tid < 64) {
      float a4 = 0.0f;
#pragma unroll
      for (int k8 = 0; k8 < 16; ++k8) {
        union { bf16x8 v; unsigned short u[8]; } h;
        h.v = *(const bf16x8*)(sAct + tid * 136 + k8 * 8);
#pragma unroll
        for (int jj = 0; jj < 8; ++jj)
          a4 = fmaf(bf2f(h.u[jj]), sWo[512 + k8 * 8 + jj], a4);
      }
      out[(b * 64 + tid) * 5 + 4] = a4 + b_o[4];
    }
  }
}

extern "C" void kernel_launch(void* const* d_in, const int* in_sizes, int n_in,
                              void* d_out, int out_size, void* d_ws, size_t ws_size,
                              hipStream_t stream) {
  const float* x    = (const float*)d_in[0];
  const float* gso  = (const float*)d_in[1];
  const float* w_c1 = (const float*)d_in[2];
  const float* b_c1 = (const float*)d_in[3];
  const float* g_b1 = (const float*)d_in[4];
  const float* e_b1 = (const float*)d_in[5];
  const float* w_c2 = (const float*)d_in[6];
  const float* b_c2 = (const float*)d_in[7];
  const float* g_b2 = (const float*)d_in[8];
  const float* e_b2 = (const float*)d_in[9];
  const float* w_c3 = (const float*)d_in[10];
  const float* b_c3 = (const float*)d_in[11];
  const float* g_b3 = (const float*)d_in[12];
  const float* e_b3 = (const float*)d_in[13];
  const float* w_fc = (const float*)d_in[14];
  const float* b_fc = (const float*)d_in[15];
  const float* w_g1 = (const float*)d_in[16];
  const float* b_g1 = (const float*)d_in[17];
  const float* w_g2 = (const float*)d_in[18];
  const float* b_g2 = (const float*)d_in[19];
  const float* w_o  = (const float*)d_in[20];
  const float* b_o  = (const float*)d_in[21];
  float* out = (float*)d_out;
  char* ws = (char*)d_ws;

  // workspace layout (bytes) — NO ALIASING, total 29.65 MB
  short* c1  = (short*)(ws + 0);          // 16,777,216
  short* c2  = (short*)(ws + 16777216);   //  8,388,608
  short* c3  = (short*)(ws + 25165824);   //  4,194,304
  short* B1  = (short*)(ws + 29360128);   //  4,096
  short* B2  = (short*)(ws + 29364224);   //  36,864
  short* B3  = (short*)(ws + 29401088);   //  147,456
  short* Wfc = (short*)(ws + 29548544);   //  32,768
  short* Wg1 = (short*)(ws + 29581312);   //  32,768
  short* Wg2 = (short*)(ws + 29614080);   //  32,768

  pack_all<<<560, 256, 0, stream>>>(w_c1, w_c2, w_c3, w_fc, w_g1, w_g2,
                                    B1, B2, B3, Wfc, Wg1, Wg2);
  conv1_mfma<<<2048, 256, 0, stream>>>(x, B1, b_c1, g_b1, e_b1, c1);
  conv2_mfma<<<512, 256, 0, stream>>>(c1, B2, b_c2, g_b2, e_b2, c2);
  conv3_mfma<<<1024, 256, 0, stream>>>(c2, B3, b_c3, g_b3, e_b3, c3);
  fused_dense<<<256, 256, 0, stream>>>(c3, gso, Wfc, Wg1, Wg2, b_fc, b_g1,
                                       b_g2, w_o, b_o, out);
}